// Round 7
// baseline (1450.053 us; speedup 1.0000x reference)
//
#include <hip/hip_runtime.h>
#include <math.h>

#define U_ 8192
#define I_ 8192
#define D_ 128
#define E_ 524288
#define N_ 16384
#define K_ 32
#define CAP_ 512

typedef unsigned short u16;
typedef unsigned int u32;
typedef unsigned long long u64;
typedef __attribute__((ext_vector_type(8))) short bf16x8;
typedef __attribute__((ext_vector_type(4))) float f32x4;

// ---------------------------------------------------------------- init ------
__global__ void k_init(const float* __restrict__ wq, const float* __restrict__ wk,
                       const float* __restrict__ bq, const float* __restrict__ wv,
                       const float* __restrict__ fw,
                       float* __restrict__ M, float* __restrict__ bqk,
                       float* __restrict__ wvT, float* __restrict__ fwdT,
                       int* __restrict__ cnt, float* __restrict__ cs1,
                       float* __restrict__ cs2,
                       float* __restrict__ svec, int* __restrict__ gcount,
                       int* __restrict__ failn) {
  const int tid = blockIdx.x * 256 + threadIdx.x;   // 64 blocks -> 16384 threads
  cnt[tid] = 0;
  gcount[tid] = 0;
  if (tid < 2048) { cs1[tid] = 0.f; cs2[tid] = 0.f; }   // 16 replicas x 128
  if (tid < 128) svec[tid] = 0.f;
  if (tid == 0) *failn = 0;
  // M[i][j] = sum_l wq[l,i]*wk[l,j]  (wq^T wk)
  const int i = tid >> 7, j = tid & 127;
  float s = 0.f;
  for (int l = 0; l < 128; ++l) s += wq[l * 128 + i] * wk[l * 128 + j];
  M[tid] = s;
  wvT[i * 128 + j] = wv[j * 128 + i];
  fwdT[i * 128 + j] = fw[j * 128 + i];   // fwdT[d][j] = fw[j][d] (d-major)
  if (tid < 128) {
    float s2 = 0.f;
    for (int l = 0; l < 128; ++l) s2 += bq[l] * wk[l * 128 + tid];
    bqk[tid] = s2;
  }
}

__global__ void k_concat(const float* __restrict__ user, const float* __restrict__ item,
                         float* __restrict__ ego) {
  const int i = blockIdx.x * 256 + threadIdx.x;     // 8192 blocks, exact
  ego[i] = (i < U_ * D_) ? user[i] : item[i - U_ * D_];
}

// ---------------------------------------------------------------- CSR -------
__global__ void k_hist(const int* __restrict__ rows, int* __restrict__ cnt) {
  const int e = blockIdx.x * 256 + threadIdx.x;     // 2048 blocks, exact
  atomicAdd(&cnt[rows[e]], 1);
}

// wave-scan: shfl_up intra-wave + 16-partial scan; 4 barriers/chunk.
__global__ void k_scan(const int* __restrict__ cnt, int* __restrict__ row_ptr,
                       int* __restrict__ cursor) {
  __shared__ int wsum[16];
  __shared__ int carry_s;
  const int t = threadIdx.x;                 // 1024 threads
  const int lane = t & 63, wid = t >> 6;
  if (t == 0) carry_s = 0;
  __syncthreads();
  for (int c = 0; c < N_ / 1024; ++c) {
    const int x = cnt[c * 1024 + t];
    int incl = x;
#pragma unroll
    for (int off = 1; off < 64; off <<= 1) {
      const int v = __shfl_up(incl, off, 64);
      if (lane >= off) incl += v;
    }
    if (lane == 63) wsum[wid] = incl;
    __syncthreads();
    if (wid == 0) {
      int s = (lane < 16) ? wsum[lane] : 0;
#pragma unroll
      for (int off = 1; off < 16; off <<= 1) {
        const int v = __shfl_up(s, off, 64);
        if (lane >= off) s += v;
      }
      if (lane < 16) wsum[lane] = s;
    }
    __syncthreads();
    const int carry = carry_s;
    const int wbase = wid ? wsum[wid - 1] : 0;
    const int excl = carry + wbase + incl - x;
    row_ptr[c * 1024 + t] = excl;
    cursor[c * 1024 + t] = excl;
    __syncthreads();
    if (t == 1023) carry_s += wsum[15];
    __syncthreads();
  }
  if (t == 0) row_ptr[N_] = carry_s;
}

__global__ void k_scatter(const int* __restrict__ rows, const int* __restrict__ cols,
                          const float* __restrict__ vals, int* __restrict__ cursor,
                          int* __restrict__ ccol, float* __restrict__ cval) {
  const int e = blockIdx.x * 256 + threadIdx.x;
  const int r = rows[e];
  const int p = atomicAdd(&cursor[r], 1);
  ccol[p] = cols[e];
  cval[p] = vals[e];
}

// ---------------------------------------------------------------- SpMM ------
__global__ __launch_bounds__(128) void k_spmm(const float* __restrict__ x,
                                              float* __restrict__ y,
                                              float* __restrict__ sum,
                                              const int* __restrict__ row_ptr,
                                              const int* __restrict__ ccol,
                                              const float* __restrict__ cval,
                                              const int first) {
  const int r = blockIdx.x, d = threadIdx.x;
  const int b = row_ptr[r], e = row_ptr[r + 1];
  double acc = 0.0;
  for (int i = b; i < e; ++i)
    acc += (double)cval[i] * (double)x[ccol[i] * 128 + d];
  const float f = (float)acc;
  y[r * 128 + d] = f;
  if (first) sum[r * 128 + d] = f; else sum[r * 128 + d] += f;
}

__global__ void k_div3(float* __restrict__ a) {
  const int i = blockIdx.x * 256 + threadIdx.x;
  a[i] = a[i] / 3.0f;
}

// ------------------------------------------------- split + transpose --------
__global__ __launch_bounds__(256) void k_split_t(const float* __restrict__ x,
                                                 u16* __restrict__ Gh, u16* __restrict__ Gl,
                                                 u16* __restrict__ XTh, u16* __restrict__ XTl,
                                                 float* __restrict__ svec) {
  __shared__ u16 lh[128 * 66];
  __shared__ u16 ll[128 * 66];
  const int tid = threadIdx.x;
  const int r0 = blockIdx.x * 64;
  float colsum = 0.f;
  for (int s = 0; s < 32; ++s) {
    const int idx = tid + s * 256;
    const int r = idx >> 7, d = idx & 127;
    const float v = x[(r0 + r) * 128 + d];
    colsum += v;
    unsigned int u = __float_as_uint(v);
    u += 0x7fffu + ((u >> 16) & 1u);
    const u16 h = (u16)(u >> 16);
    const float hf = __uint_as_float(((unsigned int)h) << 16);
    const float l = v - hf;
    unsigned int u2 = __float_as_uint(l);
    u2 += 0x7fffu + ((u2 >> 16) & 1u);
    const u16 lo = (u16)(u2 >> 16);
    Gh[(r0 + r) * 128 + d] = h;
    Gl[(r0 + r) * 128 + d] = lo;
    lh[d * 66 + r] = h;
    ll[d * 66 + r] = lo;
  }
  atomicAdd(&svec[tid & 127], colsum);
  __syncthreads();
  for (int s = 0; s < 32; ++s) {
    const int idx = tid + s * 256;
    const int d = idx >> 6, rr = idx & 63;
    XTh[d * 16384 + r0 + rr] = lh[d * 66 + rr];
    XTl[d * 16384 + r0 + rr] = ll[d * 66 + rr];
  }
}

// ---------------------------------------------------------------- C2 --------
// v2: 256 blocks (was 32 -> only 12.5% of CUs busy, latency-bound
// uncoalesced XT loads with nothing to hide them, plus a 0.5M global-atomic
// epilogue into a 64KB cross-XCD-bounced region).  Each block now covers 64
// K-nodes (2 ks iters).  The block's 256 threads hold DISJOINT C2 elements
// (w,a,kq,i,b,n16 -> unique (row,col)), so each block plain-stores its full
// 128x128 partial to a private slab; k_c2red sums the 256 slabs.  No atomics.
__global__ __launch_bounds__(256) void k_c2mfma(const u16* __restrict__ XTh,
                                                const u16* __restrict__ XTl,
                                                float* __restrict__ C2part) {
  const int tid = threadIdx.x, w = tid >> 6, lane = tid & 63;
  const int n16 = lane & 15, kq = lane >> 4;
  const int c0 = blockIdx.x * 64;
  f32x4 acc[2][8];
#pragma unroll
  for (int a = 0; a < 2; ++a)
#pragma unroll
    for (int b = 0; b < 8; ++b) acc[a][b] = (f32x4){0.f, 0.f, 0.f, 0.f};
  for (int ks = 0; ks < 2; ++ks) {
    const int c = c0 + ks * 32 + kq * 8;
    bf16x8 Fh[8], Fl[8];
#pragma unroll
    for (int g = 0; g < 8; ++g) {
      const int base = (g * 16 + n16) * 16384 + c;
      Fh[g] = *(const bf16x8*)&XTh[base];
      Fl[g] = *(const bf16x8*)&XTl[base];
    }
#pragma unroll
    for (int a = 0; a < 2; ++a) {
      const int tr = w * 2 + a;
#pragma unroll
      for (int b = 0; b < 8; ++b) {
        acc[a][b] = __builtin_amdgcn_mfma_f32_16x16x32_bf16(Fl[tr], Fh[b], acc[a][b], 0, 0, 0);
        acc[a][b] = __builtin_amdgcn_mfma_f32_16x16x32_bf16(Fh[tr], Fl[b], acc[a][b], 0, 0, 0);
        acc[a][b] = __builtin_amdgcn_mfma_f32_16x16x32_bf16(Fh[tr], Fh[b], acc[a][b], 0, 0, 0);
      }
    }
  }
  float* dst = C2part + (size_t)blockIdx.x * 16384;
#pragma unroll
  for (int a = 0; a < 2; ++a) {
    const int tr = w * 2 + a;
#pragma unroll
    for (int b = 0; b < 8; ++b)
#pragma unroll
      for (int i = 0; i < 4; ++i)
        dst[(tr * 16 + kq * 4 + i) * 128 + b * 16 + n16] = acc[a][b][i];
  }
}

__global__ void k_c2red(const float* __restrict__ C2part, float* __restrict__ C2) {
  const int e = blockIdx.x * 256 + threadIdx.x;   // 64 blocks -> 16384
  float s = 0.f;
  for (int b = 0; b < 256; ++b) s += C2part[(size_t)b * 16384 + e];
  C2[e] = s;
}

// tau_r = mean_r + 2.55 * sigma_r. Containment is STRUCTURAL: count>=36
// guarantees the top-32 (by our scores) all exceed tau; tau only trades
// candidate volume vs fallback frequency.
__global__ __launch_bounds__(128) void k_tau(const float* __restrict__ x,
                                             const float* __restrict__ C2,
                                             const float* __restrict__ svec,
                                             float* __restrict__ tau) {
  __shared__ float xs[128];
  __shared__ double red[128];
  const int n = blockIdx.x, tid = threadIdx.x;
  xs[tid] = x[n * 128 + tid];
  __syncthreads();
  double y = 0.0;
  for (int k2 = 0; k2 < 128; ++k2) y += (double)xs[k2] * (double)C2[k2 * 128 + tid];
  red[tid] = (double)xs[tid] * y;
  __syncthreads();
  for (int s = 64; s; s >>= 1) { if (tid < s) red[tid] += red[tid + s]; __syncthreads(); }
  const double exy = red[0] / 16384.0;
  __syncthreads();
  red[tid] = (double)xs[tid] * (double)svec[tid];
  __syncthreads();
  for (int s = 64; s; s >>= 1) { if (tid < s) red[tid] += red[tid + s]; __syncthreads(); }
  if (tid == 0) {
    const double m = red[0] / 16384.0;
    double var = exy - m * m;
    if (var < 0.0) var = 0.0;
    tau[n] = (float)(m + 2.55 * sqrt(var));
  }
}

// ---------------------------------------------------------------- qk --------
// v2: thin-tile matmul, 2048 blocks x 256 threads, 8 rows/block in 4KB LDS.
__global__ __launch_bounds__(256) void k_qk(const float* __restrict__ ego,
                                            const float* __restrict__ M,
                                            const float* __restrict__ bqk,
                                            float* __restrict__ qkout) {
  __shared__ float xs[8][128];
  const int tid = threadIdx.x;
  const int r0 = blockIdx.x * 8;
#pragma unroll
  for (int s = 0; s < 4; ++s) {
    const int idx = tid + s * 256;
    xs[idx >> 7][idx & 127] = ego[r0 * 128 + idx];
  }
  __syncthreads();
  const int j = tid & 127, h = tid >> 7;
  const float bj = bqk[j];
  float acc[4];
#pragma unroll
  for (int r = 0; r < 4; ++r) acc[r] = bj;
  for (int d = 0; d < 128; d += 4) {
    const float w0 = M[(d + 0) * 128 + j];
    const float w1 = M[(d + 1) * 128 + j];
    const float w2 = M[(d + 2) * 128 + j];
    const float w3 = M[(d + 3) * 128 + j];
#pragma unroll
    for (int r = 0; r < 4; ++r) {
      const float4 xv = *(const float4*)&xs[h * 4 + r][d];
      acc[r] += xv.x * w0 + xv.y * w1 + xv.z * w2 + xv.w * w3;
    }
  }
#pragma unroll
  for (int r = 0; r < 4; ++r)
    qkout[(r0 + h * 4 + r) * 128 + j] = acc[r];
}

// ------------------------------------------------------- sim via MFMA -------
// Round-7: HALF-STRIP split of the round-4/6 winner.  4096 blocks; block
// (rgrp, strip, half) covers 8 of the 16 st-subtiles -> 2x scheduling
// granularity, halved per-block serial chain, smoother tail (occupancy was
// 39% with exactly 8 coarse blocks/CU).  Inner code unchanged.  Bookkeeping:
// 32 sub-segments of 16 per row (sub = strip*2+half); per-sub cap 16
// (P[Poisson(2.7)>16]~1e-9, guarded by the fallback net like any count
// violation).  Candidate set and (val desc, col asc) order unchanged.
__global__ __launch_bounds__(256) void k_simmfma(const u16* __restrict__ Gh,
                                                 const u16* __restrict__ Gl,
                                                 const float* __restrict__ tau,
                                                 int* __restrict__ gstripcnt,
                                                 int2* __restrict__ gbuf) {
  __shared__ u16 lh[64 * 136];
  __shared__ int cnt128[128];
  const int tid = threadIdx.x;
  const int w = tid >> 6, lane = tid & 63;
  const int bid = blockIdx.x;
  const int half = bid & 1;
  const int strip = (bid >> 1) & 15;
  const int rgrp = bid >> 5;
  const int sub = strip * 2 + half;          // 0..31
  const int n16 = lane & 15, kq = lane >> 4;

  if (tid < 128) cnt128[tid] = 0;

  const int rowbase = rgrp * 128 + w * 32;
  bf16x8 Bh[2][4], Bl[2][4];
#pragma unroll
  for (int rg = 0; rg < 2; ++rg) {
    const int row = rowbase + rg * 16 + n16;
#pragma unroll
    for (int q = 0; q < 4; ++q) {
      Bh[rg][q] = *(const bf16x8*)&Gh[row * 128 + q * 32 + kq * 8];
      Bl[rg][q] = *(const bf16x8*)&Gl[row * 128 + q * 32 + kq * 8];
    }
  }
  const float tau0 = tau[rowbase + n16];
  const float tau1 = tau[rowbase + 16 + n16];
  const int col0 = strip * 1024;
  const int cst = tid >> 2, seg = tid & 3;

  const int st0 = half * 8, st1 = st0 + 8;
  for (int st = st0; st < st1; ++st) {
    const int cb = col0 + st * 64;
    __syncthreads();
#pragma unroll
    for (int i = 0; i < 4; ++i) {
      *(uint4*)&lh[cst * 136 + seg * 32 + i * 8] =
          *(const uint4*)&Gh[(cb + cst) * 128 + seg * 32 + i * 8];
    }
    __syncthreads();
#pragma unroll
    for (int ct = 0; ct < 4; ++ct) {
      bf16x8 Ah[4];
#pragma unroll
      for (int q = 0; q < 4; ++q)
        Ah[q] = *(const bf16x8*)&lh[(ct * 16 + n16) * 136 + q * 32 + kq * 8];
#pragma unroll
      for (int rg = 0; rg < 2; ++rg) {
        f32x4 p = {0.f, 0.f, 0.f, 0.f};
        f32x4 r = {0.f, 0.f, 0.f, 0.f};
#pragma unroll
        for (int q = 0; q < 4; ++q) {
          p = __builtin_amdgcn_mfma_f32_16x16x32_bf16(Ah[q], Bh[rg][q], p, 0, 0, 0);
          r = __builtin_amdgcn_mfma_f32_16x16x32_bf16(Ah[q], Bl[rg][q], r, 0, 0, 0);
        }
        const float tv = rg ? tau1 : tau0;
        const int lrow = w * 32 + rg * 16 + n16;     // block-local row 0..127
        const int row = rgrp * 128 + lrow;
#pragma unroll
        for (int i = 0; i < 4; ++i) {
          const float v = p[i] + r[i];
          if (v > tv) {
            const int c = cb + ct * 16 + kq * 4 + i;
            const int pos = atomicAdd(&cnt128[lrow], 1);   // LDS atomic
            if (pos < 16)
              gbuf[row * CAP_ + sub * 16 + pos] = make_int2(c, __float_as_int(v));
          }
        }
      }
    }
  }
  __syncthreads();
  if (tid < 128) gstripcnt[(rgrp * 128 + tid) * 32 + sub] = cnt128[tid];
}

// rows whose candidate counts violate {total in [36,CAP_], every sub<=16}
// go to the exact fallback
__global__ void k_check(const int* __restrict__ gstripcnt, int* __restrict__ failq,
                        int* __restrict__ failn) {
  const int n = blockIdx.x * 256 + threadIdx.x;   // 64 blocks
  int total = 0; int over = 0;
#pragma unroll
  for (int s = 0; s < 32; ++s) {
    const int c = gstripcnt[n * 32 + s];
    total += c;
    over |= (c > 16);
  }
  if (total < 36 || total > CAP_ || over) {
    const int s = atomicAdd(failn, 1);
    if (s < 64) failq[s] = n;
  }
}

// Top-32 by stored fp32 sim values via RANK-SCATTER on packed u64 keys:
// key = (sortable_f32 << 32) | (16383 - col)  -> (val desc, col asc) order.
// Candidates gathered from the 32 per-sub segments; col recovered from
// the key's low 32 bits. One wave per row.
__global__ __launch_bounds__(256) void k_refine(const int* __restrict__ gstripcnt,
                                                const int2* __restrict__ gbuf,
                                                int* __restrict__ topk_idx) {
  __shared__ u64 lk[4][CAP_];
  const int tid = threadIdx.x, w = tid >> 6, lane = tid & 63;
  const int n = blockIdx.x * 4 + w;

  const int scn = (lane < 32) ? gstripcnt[n * 32 + lane] : 0;
  int total = 0, over = 0;
#pragma unroll
  for (int s = 0; s < 32; ++s) {
    const int c = __shfl(scn, s, 64);
    total += c;
    over |= (c > 16);
  }
  const int bad = (total < 36 || total > CAP_ || over);
  const int cnt = bad ? 0 : total;

  // compact the 32 segments into lk[w][0..cnt)
  int base = 0;
#pragma unroll
  for (int s = 0; s < 32; ++s) {
    const int c = __shfl(scn, s, 64);
    if (!bad && lane < c) {
      const int2 p = gbuf[n * CAP_ + s * 16 + lane];
      u32 uv = (u32)p.y;
      uv = (uv >> 31) ? ~uv : (uv | 0x80000000u);
      lk[w][base + lane] = ((u64)uv << 32) | (u64)(16383 - p.x);
    }
    base += bad ? 0 : c;
  }
  __syncthreads();

  for (int ci = lane; ci < cnt; ci += 64) {
    const u64 kk = lk[w][ci];
    int r = 0;
#pragma unroll 4
    for (int j = 0; j < cnt; ++j)
      r += (lk[w][j] > kk) ? 1 : 0;
    if (r < 32) topk_idx[n * 32 + r] = 16383 - (int)(u32)(kk & 0xffffffffu);
  }
  if (bad && lane < 32) topk_idx[n * 32 + lane] = 0;  // placeholder; fallback overwrites
}

// exact fp64 full-row top-32 for statistically-failed rows (expected: none)
__global__ __launch_bounds__(256) void k_fallback(const float* __restrict__ x,
                                                  const int* __restrict__ failq,
                                                  const int* __restrict__ failn,
                                                  double* __restrict__ fsim,
                                                  int* __restrict__ topk_idx) {
  const int nf = *failn;
  const int which = blockIdx.x;
  if (which >= nf || which >= 64) return;
  const int row = failq[which];
  __shared__ float xs[128];
  __shared__ double bm[256];
  __shared__ int bc[256];
  const int tid = threadIdx.x;
  if (tid < 128) xs[tid] = x[row * 128 + tid];
  __syncthreads();
  double* fs = fsim + (size_t)which * 16384;
  for (int c = tid; c < 16384; c += 256) {
    const float4* xp = (const float4*)&x[c * 128];
    double a = 0.0;
    for (int d = 0; d < 32; ++d) {
      const float4 v = xp[d];
      a += (double)xs[d * 4 + 0] * (double)v.x + (double)xs[d * 4 + 1] * (double)v.y +
           (double)xs[d * 4 + 2] * (double)v.z + (double)xs[d * 4 + 3] * (double)v.w;
    }
    fs[c] = a;
  }
  __syncthreads();
  for (int r = 0; r < 32; ++r) {
    double m = -1.0e300; int mc = 0;
    for (int c = tid; c < 16384; c += 256) {
      const double v = fs[c];
      if (v > m || (v == m && c < mc)) { m = v; mc = c; }
    }
    bm[tid] = m; bc[tid] = mc;
    __syncthreads();
    for (int s = 128; s; s >>= 1) {
      if (tid < s) {
        if (bm[tid + s] > bm[tid] || (bm[tid + s] == bm[tid] && bc[tid + s] < bc[tid])) {
          bm[tid] = bm[tid + s]; bc[tid] = bc[tid + s];
        }
      }
      __syncthreads();
    }
    if (tid == 0) { topk_idx[row * 32 + r] = bc[0]; fs[bc[0]] = -1.0e300; }
    __syncthreads();
  }
}

// ------------------------------------------------------- attention ----------
__global__ __launch_bounds__(128) void k_attn(const float* __restrict__ ego,
                                              const float* __restrict__ qk,
                                              const int* __restrict__ topk_idx,
                                              const float* __restrict__ wvT,
                                              const float* __restrict__ bv,
                                              float* __restrict__ atten) {
  __shared__ float qv[128];
  __shared__ float sm[32 * 129];
  __shared__ int tki[32];
  __shared__ float sc[32];
  __shared__ float sa[128];
  __shared__ float psum[128];
  const int n = blockIdx.x, tid = threadIdx.x;
  qv[tid] = qk[n * 128 + tid];
  if (tid < 32) tki[tid] = topk_idx[n * 32 + tid] & 16383;
  __syncthreads();
  for (int e = tid; e < 32 * 128; e += 128) {
    const int k2 = e >> 7, d = e & 127;
    sm[k2 * 129 + d] = ego[tki[k2] * 128 + d];
  }
  __syncthreads();
  {
    const int kk = tid & 31, part = tid >> 5;
    float s = 0.f;
    const int d0 = part * 32;
    for (int d = d0; d < d0 + 32; ++d) s += qv[d] * sm[kk * 129 + d];
    psum[tid] = s;
  }
  __syncthreads();
  if (tid < 32) {
    float v = psum[tid] + psum[tid + 32] + psum[tid + 64] + psum[tid + 96];
    v *= (1.0f / 11.313708498984760f);    // 1/sqrt(128)
    float m = v;
#pragma unroll
    for (int off = 16; off; off >>= 1) m = fmaxf(m, __shfl_xor(m, off, 32));
    const float e = expf(v - m);
    float ssum = e;
#pragma unroll
    for (int off = 16; off; off >>= 1) ssum += __shfl_xor(ssum, off, 32);
    sc[tid] = e / ssum;
  }
  __syncthreads();
  float sad = 0.f;
  for (int k2 = 0; k2 < 32; ++k2) sad += sc[k2] * sm[k2 * 129 + tid];
  sa[tid] = sad;
  __syncthreads();
  float o = bv[tid];
  for (int d = 0; d < 128; ++d) o += sa[d] * wvT[d * 128 + tid];
  atten[n * 128 + tid] = o + 0.1f * ego[n * 128 + tid];
}

// ------------------------------------------------------- fusion -------------
__global__ __launch_bounds__(256) void k_fuse1(const float* __restrict__ allemb,
                                               const float* __restrict__ atten,
                                               const float* __restrict__ fwdT,
                                               const float* __restrict__ fb,
                                               float* __restrict__ z1,
                                               float* __restrict__ z2,
                                               float* __restrict__ cs1,
                                               float* __restrict__ cs2) {
  __shared__ float xs[8][128];
  __shared__ float as[8][128];
  __shared__ float red1[2][128];
  __shared__ float red2[2][128];
  const int tid = threadIdx.x;
  const int r0 = blockIdx.x * 8;
#pragma unroll
  for (int s = 0; s < 4; ++s) {
    const int idx = tid + s * 256;
    const int rr = idx >> 7, d = idx & 127;
    xs[rr][d] = allemb[(r0 + rr) * 128 + d];
    as[rr][d] = atten[(r0 + rr) * 128 + d];
  }
  __syncthreads();
  const int j = tid & 127, h = tid >> 7;
  const float fbj = fb[j];
  float acc1[4], acc2[4];
#pragma unroll
  for (int r = 0; r < 4; ++r) { acc1[r] = fbj; acc2[r] = fbj; }
  for (int d = 0; d < 128; d += 4) {
    const float w0 = fwdT[(d + 0) * 128 + j];
    const float w1 = fwdT[(d + 1) * 128 + j];
    const float w2 = fwdT[(d + 2) * 128 + j];
    const float w3 = fwdT[(d + 3) * 128 + j];
#pragma unroll
    for (int r = 0; r < 4; ++r) {
      const int rr = h * 4 + r;
      const float4 xv = *(const float4*)&xs[rr][d];
      const float4 av = *(const float4*)&as[rr][d];
      acc1[r] += xv.x * w0 + xv.y * w1 + xv.z * w2 + xv.w * w3;
      acc2[r] += av.x * w0 + av.y * w1 + av.z * w2 + av.w * w3;
    }
  }
  float ls1 = 0.f, ls2 = 0.f;
#pragma unroll
  for (int r = 0; r < 4; ++r) {
    const int rr = h * 4 + r;
    const float t1 = tanhf(acc1[r]);
    const float t2 = tanhf(acc2[r]);
    z1[(r0 + rr) * 128 + j] = t1;
    z2[(r0 + rr) * 128 + j] = t2;
    ls1 += expf(t1 - 1.0f);
    ls2 += expf(t2 - 1.0f);
  }
  red1[h][j] = ls1;
  red2[h][j] = ls2;
  __syncthreads();
  if (h == 0) {
    const int rep = blockIdx.x & 15;
    atomicAdd(&cs1[rep * 128 + j], red1[0][j] + red1[1][j]);
    atomicAdd(&cs2[rep * 128 + j], red2[0][j] + red2[1][j]);
  }
}

__global__ void k_fuse2(const float* __restrict__ allemb, const float* __restrict__ atten,
                        const float* __restrict__ z1, const float* __restrict__ z2,
                        const float* __restrict__ cs1, const float* __restrict__ cs2,
                        float* __restrict__ fusion) {
  __shared__ float s1[128], s2[128];
  const int tid = threadIdx.x;
  if (tid < 128) {
    float a = 0.f, b = 0.f;
#pragma unroll
    for (int rep = 0; rep < 16; ++rep) {
      a += cs1[rep * 128 + tid];
      b += cs2[rep * 128 + tid];
    }
    s1[tid] = a; s2[tid] = b;
  }
  __syncthreads();
  const int i = blockIdx.x * 256 + tid;
  const int j = i & 127;
  const float a1 = expf(z1[i] - 1.0f) / s1[j];
  const float a2 = expf(z2[i] - 1.0f) / s2[j];
  fusion[i] = a1 * allemb[i] + a2 * atten[i];
}

// ---------------------------------------------------------------- launch ----
extern "C" void kernel_launch(void* const* d_in, const int* in_sizes, int n_in,
                              void* d_out, int out_size, void* d_ws, size_t ws_size,
                              hipStream_t stream) {
  (void)in_sizes; (void)n_in; (void)out_size; (void)ws_size;
  const float* user = (const float*)d_in[0];
  const float* item = (const float*)d_in[1];
  const int* adj_rows = (const int*)d_in[2];
  const int* adj_cols = (const int*)d_in[3];
  const float* adj_vals = (const float*)d_in[4];
  const float* wq = (const float*)d_in[5];
  const float* bq = (const float*)d_in[6];
  const float* wk = (const float*)d_in[7];
  const float* wv = (const float*)d_in[9];
  const float* bv = (const float*)d_in[10];
  const float* fw = (const float*)d_in[11];
  const float* fb = (const float*)d_in[12];

  float* out = (float*)d_out;
  float* allemb = out;                    // [N,D]
  float* atten = out + (size_t)N_ * D_;   // [N,D]
  float* fusion = out + (size_t)2 * N_ * D_;

  char* ws = (char*)d_ws;
  size_t off = 0;
  auto alloc = [&](size_t bytes) { char* p = ws + off; off += (bytes + 255) & ~(size_t)255; return p; };
  float* ego_a = (float*)alloc((size_t)N_ * D_ * 4);
  float* ego_b = (float*)alloc((size_t)N_ * D_ * 4);
  float* qkbuf = (float*)alloc((size_t)N_ * D_ * 4);
  u16* Gh = (u16*)alloc((size_t)N_ * D_ * 2);
  u16* Gl = (u16*)alloc((size_t)N_ * D_ * 2);
  u16* XTh = (u16*)alloc((size_t)N_ * D_ * 2);
  u16* XTl = (u16*)alloc((size_t)N_ * D_ * 2);
  int2* gbuf = (int2*)alloc((size_t)N_ * CAP_ * 8);  // (col,val) pairs (aliased by z1)
  float* z1 = (float*)gbuf;                          // lifetimes disjoint
  float* z2 = (float*)alloc((size_t)N_ * D_ * 4);
  int* topk_idx = (int*)alloc((size_t)N_ * 32 * 4);
  int* ccol = (int*)alloc((size_t)E_ * 4);
  float* cval = (float*)alloc((size_t)E_ * 4);
  int* cnt = (int*)alloc((size_t)N_ * 4);
  int* row_ptr = (int*)alloc((size_t)(N_ + 1) * 4);
  int* cursor = (int*)alloc((size_t)N_ * 4);
  float* M = (float*)alloc(128 * 128 * 4);
  float* bqk = (float*)alloc(128 * 4);
  float* wvT = (float*)alloc(128 * 128 * 4);
  float* fwdT = (float*)alloc(128 * 128 * 4);
  float* cs1 = (float*)alloc(16 * 128 * 4);           // 16 replicas
  float* cs2 = (float*)alloc(16 * 128 * 4);
  float* C2 = (float*)alloc(128 * 128 * 4);
  float* C2part = (float*)alloc((size_t)256 * 16384 * 4);   // 16 MB partials
  float* svec = (float*)alloc(128 * 4);
  float* tau = (float*)alloc((size_t)N_ * 4);
  int* gcount = (int*)alloc((size_t)N_ * 4);          // legacy (unused by hot path)
  int* gstripcnt = (int*)alloc((size_t)N_ * 32 * 4);  // per (row,sub) counts
  int* failq = (int*)alloc(64 * 4);
  int* failn = (int*)alloc(4);
  double* fsim = (double*)alloc((size_t)64 * N_ * 8);

  k_init<<<64, 256, 0, stream>>>(wq, wk, bq, wv, fw, M, bqk, wvT, fwdT, cnt, cs1, cs2, svec, gcount, failn);
  k_concat<<<8192, 256, 0, stream>>>(user, item, ego_a);
  k_hist<<<2048, 256, 0, stream>>>(adj_rows, cnt);
  k_scan<<<1, 1024, 0, stream>>>(cnt, row_ptr, cursor);
  k_scatter<<<2048, 256, 0, stream>>>(adj_rows, adj_cols, adj_vals, cursor, ccol, cval);

  k_spmm<<<N_, 128, 0, stream>>>(ego_a, ego_b, allemb, row_ptr, ccol, cval, 1);
  k_spmm<<<N_, 128, 0, stream>>>(ego_b, ego_a, allemb, row_ptr, ccol, cval, 0);
  k_spmm<<<N_, 128, 0, stream>>>(ego_a, ego_b, allemb, row_ptr, ccol, cval, 0);
  // ego3 = ego_b
  k_div3<<<8192, 256, 0, stream>>>(allemb);

  k_split_t<<<256, 256, 0, stream>>>(ego_b, Gh, Gl, XTh, XTl, svec);
  k_c2mfma<<<256, 256, 0, stream>>>(XTh, XTl, C2part);
  k_c2red<<<64, 256, 0, stream>>>(C2part, C2);
  k_tau<<<N_, 128, 0, stream>>>(ego_b, C2, svec, tau);

  k_qk<<<2048, 256, 0, stream>>>(ego_b, M, bqk, qkbuf);
  k_simmfma<<<4096, 256, 0, stream>>>(Gh, Gl, tau, gstripcnt, gbuf);   // half-strip split
  k_check<<<64, 256, 0, stream>>>(gstripcnt, failq, failn);
  k_refine<<<4096, 256, 0, stream>>>(gstripcnt, gbuf, topk_idx);
  k_fallback<<<64, 256, 0, stream>>>(ego_b, failq, failn, fsim, topk_idx);
  k_attn<<<N_, 128, 0, stream>>>(ego_b, qkbuf, topk_idx, wvT, bv, atten);

  k_fuse1<<<2048, 256, 0, stream>>>(allemb, atten, fwdT, fb, z1, z2, cs1, cs2);
  k_fuse2<<<8192, 256, 0, stream>>>(allemb, atten, z1, z2, cs1, cs2, fusion);
}

// Round 8
// 787.010 us; speedup vs baseline: 1.8425x; 1.8425x over previous
//
#include <hip/hip_runtime.h>
#include <math.h>

#define U_ 8192
#define I_ 8192
#define D_ 128
#define E_ 524288
#define N_ 16384
#define K_ 32
#define CAP_ 512

typedef unsigned short u16;
typedef unsigned int u32;
typedef unsigned long long u64;
typedef __attribute__((ext_vector_type(8))) short bf16x8;
typedef __attribute__((ext_vector_type(4))) float f32x4;

// ---------------------------------------------------------------- init ------
__global__ void k_init(const float* __restrict__ wq, const float* __restrict__ wk,
                       const float* __restrict__ bq, const float* __restrict__ wv,
                       const float* __restrict__ fw,
                       float* __restrict__ M, float* __restrict__ bqk,
                       float* __restrict__ wvT, float* __restrict__ fwdT,
                       int* __restrict__ cnt, float* __restrict__ cs1,
                       float* __restrict__ cs2,
                       float* __restrict__ svec, int* __restrict__ gcount,
                       int* __restrict__ failn) {
  const int tid = blockIdx.x * 256 + threadIdx.x;   // 64 blocks -> 16384 threads
  cnt[tid] = 0;
  gcount[tid] = 0;
  if (tid < 2048) { cs1[tid] = 0.f; cs2[tid] = 0.f; }   // 16 replicas x 128
  if (tid < 128) svec[tid] = 0.f;
  if (tid == 0) *failn = 0;
  // M[i][j] = sum_l wq[l,i]*wk[l,j]  (wq^T wk)
  const int i = tid >> 7, j = tid & 127;
  float s = 0.f;
  for (int l = 0; l < 128; ++l) s += wq[l * 128 + i] * wk[l * 128 + j];
  M[tid] = s;
  wvT[i * 128 + j] = wv[j * 128 + i];
  fwdT[i * 128 + j] = fw[j * 128 + i];   // fwdT[d][j] = fw[j][d] (d-major)
  if (tid < 128) {
    float s2 = 0.f;
    for (int l = 0; l < 128; ++l) s2 += bq[l] * wk[l * 128 + tid];
    bqk[tid] = s2;
  }
}

__global__ void k_concat(const float* __restrict__ user, const float* __restrict__ item,
                         float* __restrict__ ego) {
  const int i = blockIdx.x * 256 + threadIdx.x;     // 8192 blocks, exact
  ego[i] = (i < U_ * D_) ? user[i] : item[i - U_ * D_];
}

// ---------------------------------------------------------------- CSR -------
__global__ void k_hist(const int* __restrict__ rows, int* __restrict__ cnt) {
  const int e = blockIdx.x * 256 + threadIdx.x;     // 2048 blocks, exact
  atomicAdd(&cnt[rows[e]], 1);
}

// wave-scan: shfl_up intra-wave + 16-partial scan; 4 barriers/chunk.
__global__ void k_scan(const int* __restrict__ cnt, int* __restrict__ row_ptr,
                       int* __restrict__ cursor) {
  __shared__ int wsum[16];
  __shared__ int carry_s;
  const int t = threadIdx.x;                 // 1024 threads
  const int lane = t & 63, wid = t >> 6;
  if (t == 0) carry_s = 0;
  __syncthreads();
  for (int c = 0; c < N_ / 1024; ++c) {
    const int x = cnt[c * 1024 + t];
    int incl = x;
#pragma unroll
    for (int off = 1; off < 64; off <<= 1) {
      const int v = __shfl_up(incl, off, 64);
      if (lane >= off) incl += v;
    }
    if (lane == 63) wsum[wid] = incl;
    __syncthreads();
    if (wid == 0) {
      int s = (lane < 16) ? wsum[lane] : 0;
#pragma unroll
      for (int off = 1; off < 16; off <<= 1) {
        const int v = __shfl_up(s, off, 64);
        if (lane >= off) s += v;
      }
      if (lane < 16) wsum[lane] = s;
    }
    __syncthreads();
    const int carry = carry_s;
    const int wbase = wid ? wsum[wid - 1] : 0;
    const int excl = carry + wbase + incl - x;
    row_ptr[c * 1024 + t] = excl;
    cursor[c * 1024 + t] = excl;
    __syncthreads();
    if (t == 1023) carry_s += wsum[15];
    __syncthreads();
  }
  if (t == 0) row_ptr[N_] = carry_s;
}

__global__ void k_scatter(const int* __restrict__ rows, const int* __restrict__ cols,
                          const float* __restrict__ vals, int* __restrict__ cursor,
                          int* __restrict__ ccol, float* __restrict__ cval) {
  const int e = blockIdx.x * 256 + threadIdx.x;
  const int r = rows[e];
  const int p = atomicAdd(&cursor[r], 1);
  ccol[p] = cols[e];
  cval[p] = vals[e];
}

// ---------------------------------------------------------------- SpMM ------
__global__ __launch_bounds__(128) void k_spmm(const float* __restrict__ x,
                                              float* __restrict__ y,
                                              float* __restrict__ sum,
                                              const int* __restrict__ row_ptr,
                                              const int* __restrict__ ccol,
                                              const float* __restrict__ cval,
                                              const int first) {
  const int r = blockIdx.x, d = threadIdx.x;
  const int b = row_ptr[r], e = row_ptr[r + 1];
  double acc = 0.0;
  for (int i = b; i < e; ++i)
    acc += (double)cval[i] * (double)x[ccol[i] * 128 + d];
  const float f = (float)acc;
  y[r * 128 + d] = f;
  if (first) sum[r * 128 + d] = f; else sum[r * 128 + d] += f;
}

__global__ void k_div3(float* __restrict__ a) {
  const int i = blockIdx.x * 256 + threadIdx.x;
  a[i] = a[i] / 3.0f;
}

// ------------------------------------------------- split + transpose --------
__global__ __launch_bounds__(256) void k_split_t(const float* __restrict__ x,
                                                 u16* __restrict__ Gh, u16* __restrict__ Gl,
                                                 u16* __restrict__ XTh, u16* __restrict__ XTl,
                                                 float* __restrict__ svec) {
  __shared__ u16 lh[128 * 66];
  __shared__ u16 ll[128 * 66];
  const int tid = threadIdx.x;
  const int r0 = blockIdx.x * 64;
  float colsum = 0.f;
  for (int s = 0; s < 32; ++s) {
    const int idx = tid + s * 256;
    const int r = idx >> 7, d = idx & 127;
    const float v = x[(r0 + r) * 128 + d];
    colsum += v;
    unsigned int u = __float_as_uint(v);
    u += 0x7fffu + ((u >> 16) & 1u);
    const u16 h = (u16)(u >> 16);
    const float hf = __uint_as_float(((unsigned int)h) << 16);
    const float l = v - hf;
    unsigned int u2 = __float_as_uint(l);
    u2 += 0x7fffu + ((u2 >> 16) & 1u);
    const u16 lo = (u16)(u2 >> 16);
    Gh[(r0 + r) * 128 + d] = h;
    Gl[(r0 + r) * 128 + d] = lo;
    lh[d * 66 + r] = h;
    ll[d * 66 + r] = lo;
  }
  atomicAdd(&svec[tid & 127], colsum);
  __syncthreads();
  for (int s = 0; s < 32; ++s) {
    const int idx = tid + s * 256;
    const int d = idx >> 6, rr = idx & 63;
    XTh[d * 16384 + r0 + rr] = lh[d * 66 + rr];
    XTl[d * 16384 + r0 + rr] = ll[d * 66 + rr];
  }
}

// ---------------------------------------------------------------- C2 --------
// v2 (kept from round 7, structurally safe): 256 blocks, each covering 64
// K-nodes; threads hold disjoint C2 elements so blocks plain-store full
// 128x128 partials to private slabs; k_c2red sums them.  No atomics.
__global__ __launch_bounds__(256) void k_c2mfma(const u16* __restrict__ XTh,
                                                const u16* __restrict__ XTl,
                                                float* __restrict__ C2part) {
  const int tid = threadIdx.x, w = tid >> 6, lane = tid & 63;
  const int n16 = lane & 15, kq = lane >> 4;
  const int c0 = blockIdx.x * 64;
  f32x4 acc[2][8];
#pragma unroll
  for (int a = 0; a < 2; ++a)
#pragma unroll
    for (int b = 0; b < 8; ++b) acc[a][b] = (f32x4){0.f, 0.f, 0.f, 0.f};
  for (int ks = 0; ks < 2; ++ks) {
    const int c = c0 + ks * 32 + kq * 8;
    bf16x8 Fh[8], Fl[8];
#pragma unroll
    for (int g = 0; g < 8; ++g) {
      const int base = (g * 16 + n16) * 16384 + c;
      Fh[g] = *(const bf16x8*)&XTh[base];
      Fl[g] = *(const bf16x8*)&XTl[base];
    }
#pragma unroll
    for (int a = 0; a < 2; ++a) {
      const int tr = w * 2 + a;
#pragma unroll
      for (int b = 0; b < 8; ++b) {
        acc[a][b] = __builtin_amdgcn_mfma_f32_16x16x32_bf16(Fl[tr], Fh[b], acc[a][b], 0, 0, 0);
        acc[a][b] = __builtin_amdgcn_mfma_f32_16x16x32_bf16(Fh[tr], Fl[b], acc[a][b], 0, 0, 0);
        acc[a][b] = __builtin_amdgcn_mfma_f32_16x16x32_bf16(Fh[tr], Fh[b], acc[a][b], 0, 0, 0);
      }
    }
  }
  float* dst = C2part + (size_t)blockIdx.x * 16384;
#pragma unroll
  for (int a = 0; a < 2; ++a) {
    const int tr = w * 2 + a;
#pragma unroll
    for (int b = 0; b < 8; ++b)
#pragma unroll
      for (int i = 0; i < 4; ++i)
        dst[(tr * 16 + kq * 4 + i) * 128 + b * 16 + n16] = acc[a][b][i];
  }
}

__global__ void k_c2red(const float* __restrict__ C2part, float* __restrict__ C2) {
  const int e = blockIdx.x * 256 + threadIdx.x;   // 64 blocks -> 16384
  float s = 0.f;
  for (int b = 0; b < 256; ++b) s += C2part[(size_t)b * 16384 + e];
  C2[e] = s;
}

// tau_r = mean_r + 2.55 * sigma_r. Containment is STRUCTURAL: count>=36
// guarantees the top-32 (by our scores) all exceed tau; tau only trades
// candidate volume vs fallback frequency.
__global__ __launch_bounds__(128) void k_tau(const float* __restrict__ x,
                                             const float* __restrict__ C2,
                                             const float* __restrict__ svec,
                                             float* __restrict__ tau) {
  __shared__ float xs[128];
  __shared__ double red[128];
  const int n = blockIdx.x, tid = threadIdx.x;
  xs[tid] = x[n * 128 + tid];
  __syncthreads();
  double y = 0.0;
  for (int k2 = 0; k2 < 128; ++k2) y += (double)xs[k2] * (double)C2[k2 * 128 + tid];
  red[tid] = (double)xs[tid] * y;
  __syncthreads();
  for (int s = 64; s; s >>= 1) { if (tid < s) red[tid] += red[tid + s]; __syncthreads(); }
  const double exy = red[0] / 16384.0;
  __syncthreads();
  red[tid] = (double)xs[tid] * (double)svec[tid];
  __syncthreads();
  for (int s = 64; s; s >>= 1) { if (tid < s) red[tid] += red[tid + s]; __syncthreads(); }
  if (tid == 0) {
    const double m = red[0] / 16384.0;
    double var = exy - m * m;
    if (var < 0.0) var = 0.0;
    tau[n] = (float)(m + 2.55 * sqrt(var));
  }
}

// ---------------------------------------------------------------- qk --------
// v2: thin-tile matmul, 2048 blocks x 256 threads, 8 rows/block in 4KB LDS.
__global__ __launch_bounds__(256) void k_qk(const float* __restrict__ ego,
                                            const float* __restrict__ M,
                                            const float* __restrict__ bqk,
                                            float* __restrict__ qkout) {
  __shared__ float xs[8][128];
  const int tid = threadIdx.x;
  const int r0 = blockIdx.x * 8;
#pragma unroll
  for (int s = 0; s < 4; ++s) {
    const int idx = tid + s * 256;
    xs[idx >> 7][idx & 127] = ego[r0 * 128 + idx];
  }
  __syncthreads();
  const int j = tid & 127, h = tid >> 7;
  const float bj = bqk[j];
  float acc[4];
#pragma unroll
  for (int r = 0; r < 4; ++r) acc[r] = bj;
  for (int d = 0; d < 128; d += 4) {
    const float w0 = M[(d + 0) * 128 + j];
    const float w1 = M[(d + 1) * 128 + j];
    const float w2 = M[(d + 2) * 128 + j];
    const float w3 = M[(d + 3) * 128 + j];
#pragma unroll
    for (int r = 0; r < 4; ++r) {
      const float4 xv = *(const float4*)&xs[h * 4 + r][d];
      acc[r] += xv.x * w0 + xv.y * w1 + xv.z * w2 + xv.w * w3;
    }
  }
#pragma unroll
  for (int r = 0; r < 4; ++r)
    qkout[(r0 + h * 4 + r) * 128 + j] = acc[r];
}

// ------------------------------------------------------- sim via MFMA -------
// Round-8: REVERT to the round-6 measured winner (2048 blocks, 16 strips,
// per-strip cap 32, LDS-local counters -- 141.8us, failn~0; the round-7
// per-sub cap 16 tripped mass fallback because per-row totals reach ~512,
// not Poisson-uniform) + ONE orthogonal graft verified in round 1:
// swizzled global_load_lds staging.  LDS stays linear 256B rows; the
// global SOURCE chunk is XORed with (row&7) and reads apply the same XOR,
// spreading the 16-lane column reads across 8 bank slots (round-1 measured
// conflicts 12.6e6 -> 4.2e6) and removing the uint4 reg-roundtrip VALU.
__device__ __forceinline__ void gload_lds16(const u16* g, u16* l) {
  __builtin_amdgcn_global_load_lds(
      (const __attribute__((address_space(1))) void*)g,
      (__attribute__((address_space(3))) void*)l, 16, 0, 0);
}

__global__ __launch_bounds__(256) void k_simmfma(const u16* __restrict__ Gh,
                                                 const u16* __restrict__ Gl,
                                                 const float* __restrict__ tau,
                                                 int* __restrict__ gstripcnt,
                                                 int2* __restrict__ gbuf) {
  __shared__ __align__(16) u16 lh[64 * 128];   // 16 KB, linear 256-B rows
  __shared__ int cnt128[128];
  const int tid = threadIdx.x;
  const int w = tid >> 6, lane = tid & 63;
  const int strip = blockIdx.x & 15, rgrp = blockIdx.x >> 4;
  const int n16 = lane & 15, kq = lane >> 4;

  if (tid < 128) cnt128[tid] = 0;

  const int rowbase = rgrp * 128 + w * 32;
  bf16x8 Bh[2][4], Bl[2][4];
#pragma unroll
  for (int rg = 0; rg < 2; ++rg) {
    const int row = rowbase + rg * 16 + n16;
#pragma unroll
    for (int q = 0; q < 4; ++q) {
      Bh[rg][q] = *(const bf16x8*)&Gh[row * 128 + q * 32 + kq * 8];
      Bl[rg][q] = *(const bf16x8*)&Gl[row * 128 + q * 32 + kq * 8];
    }
  }
  const float tau0 = tau[rowbase + n16];
  const float tau1 = tau[rowbase + 16 + n16];
  const int col0 = strip * 1024;

  for (int st = 0; st < 16; ++st) {
    const int cb = col0 + st * 64;
    __syncthreads();
    // stage 64 rows x 256 B: each wave DMAs 4 rows per issue (1024 B);
    // source chunk pre-swizzled (n16 ^ row&7), LDS linear.
#pragma unroll
    for (int ii = 0; ii < 4; ++ii) {
      const int srow = w * 16 + ii * 4 + kq;
      const int chunk = n16 ^ (srow & 7);
      gload_lds16(Gh + (((size_t)(cb + srow)) << 7) + chunk * 8,
                  lh + ((w * 16 + ii * 4) << 7));
    }
    __syncthreads();   // drains vmcnt: staged tile visible to all waves
#pragma unroll
    for (int ct = 0; ct < 4; ++ct) {
      const int ar = ct * 16 + n16;
      const char* lbase = (const char*)lh + ar * 256;
      bf16x8 Ah[4];
#pragma unroll
      for (int q = 0; q < 4; ++q)
        Ah[q] = *(const bf16x8*)(lbase + ((q * 64 + kq * 16) ^ ((ar & 7) << 4)));
#pragma unroll
      for (int rg = 0; rg < 2; ++rg) {
        f32x4 p = {0.f, 0.f, 0.f, 0.f};
        f32x4 r = {0.f, 0.f, 0.f, 0.f};
#pragma unroll
        for (int q = 0; q < 4; ++q) {
          p = __builtin_amdgcn_mfma_f32_16x16x32_bf16(Ah[q], Bh[rg][q], p, 0, 0, 0);
          r = __builtin_amdgcn_mfma_f32_16x16x32_bf16(Ah[q], Bl[rg][q], r, 0, 0, 0);
        }
        const float tv = rg ? tau1 : tau0;
        const int lrow = w * 32 + rg * 16 + n16;     // block-local row 0..127
        const int row = rgrp * 128 + lrow;
#pragma unroll
        for (int i = 0; i < 4; ++i) {
          const float v = p[i] + r[i];
          if (v > tv) {
            const int c = cb + ct * 16 + kq * 4 + i;
            const int pos = atomicAdd(&cnt128[lrow], 1);   // LDS atomic
            if (pos < 32)
              gbuf[row * CAP_ + strip * 32 + pos] = make_int2(c, __float_as_int(v));
          }
        }
      }
    }
  }
  __syncthreads();
  if (tid < 128) gstripcnt[(rgrp * 128 + tid) * 16 + strip] = cnt128[tid];
}

// rows whose candidate counts violate {total in [36,CAP_], every strip<=32}
// go to the exact fallback
__global__ void k_check(const int* __restrict__ gstripcnt, int* __restrict__ failq,
                        int* __restrict__ failn) {
  const int n = blockIdx.x * 256 + threadIdx.x;   // 64 blocks
  int total = 0; int over = 0;
#pragma unroll
  for (int s = 0; s < 16; ++s) {
    const int c = gstripcnt[n * 16 + s];
    total += c;
    over |= (c > 32);
  }
  if (total < 36 || total > CAP_ || over) {
    const int s = atomicAdd(failn, 1);
    if (s < 64) failq[s] = n;
  }
}

// Top-32 by stored fp32 sim values via RANK-SCATTER on packed u64 keys:
// key = (sortable_f32 << 32) | (16383 - col)  -> (val desc, col asc) order.
// Candidates gathered from the 16 per-strip segments; col recovered from
// the key's low 32 bits. One wave per row.
__global__ __launch_bounds__(256) void k_refine(const int* __restrict__ gstripcnt,
                                                const int2* __restrict__ gbuf,
                                                int* __restrict__ topk_idx) {
  __shared__ u64 lk[4][CAP_];
  const int tid = threadIdx.x, w = tid >> 6, lane = tid & 63;
  const int n = blockIdx.x * 4 + w;

  const int scn = (lane < 16) ? gstripcnt[n * 16 + lane] : 0;
  int total = 0, over = 0;
#pragma unroll
  for (int s = 0; s < 16; ++s) {
    const int c = __shfl(scn, s, 64);
    total += c;
    over |= (c > 32);
  }
  const int bad = (total < 36 || total > CAP_ || over);
  const int cnt = bad ? 0 : total;

  // compact the 16 segments into lk[w][0..cnt)
  int base = 0;
#pragma unroll
  for (int s = 0; s < 16; ++s) {
    const int c = __shfl(scn, s, 64);
    if (!bad && lane < c) {
      const int2 p = gbuf[n * CAP_ + s * 32 + lane];
      u32 uv = (u32)p.y;
      uv = (uv >> 31) ? ~uv : (uv | 0x80000000u);
      lk[w][base + lane] = ((u64)uv << 32) | (u64)(16383 - p.x);
    }
    base += bad ? 0 : c;
  }
  __syncthreads();

  for (int ci = lane; ci < cnt; ci += 64) {
    const u64 kk = lk[w][ci];
    int r = 0;
#pragma unroll 4
    for (int j = 0; j < cnt; ++j)
      r += (lk[w][j] > kk) ? 1 : 0;
    if (r < 32) topk_idx[n * 32 + r] = 16383 - (int)(u32)(kk & 0xffffffffu);
  }
  if (bad && lane < 32) topk_idx[n * 32 + lane] = 0;  // placeholder; fallback overwrites
}

// exact fp64 full-row top-32 for statistically-failed rows (expected: none)
__global__ __launch_bounds__(256) void k_fallback(const float* __restrict__ x,
                                                  const int* __restrict__ failq,
                                                  const int* __restrict__ failn,
                                                  double* __restrict__ fsim,
                                                  int* __restrict__ topk_idx) {
  const int nf = *failn;
  const int which = blockIdx.x;
  if (which >= nf || which >= 64) return;
  const int row = failq[which];
  __shared__ float xs[128];
  __shared__ double bm[256];
  __shared__ int bc[256];
  const int tid = threadIdx.x;
  if (tid < 128) xs[tid] = x[row * 128 + tid];
  __syncthreads();
  double* fs = fsim + (size_t)which * 16384;
  for (int c = tid; c < 16384; c += 256) {
    const float4* xp = (const float4*)&x[c * 128];
    double a = 0.0;
    for (int d = 0; d < 32; ++d) {
      const float4 v = xp[d];
      a += (double)xs[d * 4 + 0] * (double)v.x + (double)xs[d * 4 + 1] * (double)v.y +
           (double)xs[d * 4 + 2] * (double)v.z + (double)xs[d * 4 + 3] * (double)v.w;
    }
    fs[c] = a;
  }
  __syncthreads();
  for (int r = 0; r < 32; ++r) {
    double m = -1.0e300; int mc = 0;
    for (int c = tid; c < 16384; c += 256) {
      const double v = fs[c];
      if (v > m || (v == m && c < mc)) { m = v; mc = c; }
    }
    bm[tid] = m; bc[tid] = mc;
    __syncthreads();
    for (int s = 128; s; s >>= 1) {
      if (tid < s) {
        if (bm[tid + s] > bm[tid] || (bm[tid + s] == bm[tid] && bc[tid + s] < bc[tid])) {
          bm[tid] = bm[tid + s]; bc[tid] = bc[tid + s];
        }
      }
      __syncthreads();
    }
    if (tid == 0) { topk_idx[row * 32 + r] = bc[0]; fs[bc[0]] = -1.0e300; }
    __syncthreads();
  }
}

// ------------------------------------------------------- attention ----------
__global__ __launch_bounds__(128) void k_attn(const float* __restrict__ ego,
                                              const float* __restrict__ qk,
                                              const int* __restrict__ topk_idx,
                                              const float* __restrict__ wvT,
                                              const float* __restrict__ bv,
                                              float* __restrict__ atten) {
  __shared__ float qv[128];
  __shared__ float sm[32 * 129];
  __shared__ int tki[32];
  __shared__ float sc[32];
  __shared__ float sa[128];
  __shared__ float psum[128];
  const int n = blockIdx.x, tid = threadIdx.x;
  qv[tid] = qk[n * 128 + tid];
  if (tid < 32) tki[tid] = topk_idx[n * 32 + tid] & 16383;
  __syncthreads();
  for (int e = tid; e < 32 * 128; e += 128) {
    const int k2 = e >> 7, d = e & 127;
    sm[k2 * 129 + d] = ego[tki[k2] * 128 + d];
  }
  __syncthreads();
  {
    const int kk = tid & 31, part = tid >> 5;
    float s = 0.f;
    const int d0 = part * 32;
    for (int d = d0; d < d0 + 32; ++d) s += qv[d] * sm[kk * 129 + d];
    psum[tid] = s;
  }
  __syncthreads();
  if (tid < 32) {
    float v = psum[tid] + psum[tid + 32] + psum[tid + 64] + psum[tid + 96];
    v *= (1.0f / 11.313708498984760f);    // 1/sqrt(128)
    float m = v;
#pragma unroll
    for (int off = 16; off; off >>= 1) m = fmaxf(m, __shfl_xor(m, off, 32));
    const float e = expf(v - m);
    float ssum = e;
#pragma unroll
    for (int off = 16; off; off >>= 1) ssum += __shfl_xor(ssum, off, 32);
    sc[tid] = e / ssum;
  }
  __syncthreads();
  float sad = 0.f;
  for (int k2 = 0; k2 < 32; ++k2) sad += sc[k2] * sm[k2 * 129 + tid];
  sa[tid] = sad;
  __syncthreads();
  float o = bv[tid];
  for (int d = 0; d < 128; ++d) o += sa[d] * wvT[d * 128 + tid];
  atten[n * 128 + tid] = o + 0.1f * ego[n * 128 + tid];
}

// ------------------------------------------------------- fusion -------------
__global__ __launch_bounds__(256) void k_fuse1(const float* __restrict__ allemb,
                                               const float* __restrict__ atten,
                                               const float* __restrict__ fwdT,
                                               const float* __restrict__ fb,
                                               float* __restrict__ z1,
                                               float* __restrict__ z2,
                                               float* __restrict__ cs1,
                                               float* __restrict__ cs2) {
  __shared__ float xs[8][128];
  __shared__ float as[8][128];
  __shared__ float red1[2][128];
  __shared__ float red2[2][128];
  const int tid = threadIdx.x;
  const int r0 = blockIdx.x * 8;
#pragma unroll
  for (int s = 0; s < 4; ++s) {
    const int idx = tid + s * 256;
    const int rr = idx >> 7, d = idx & 127;
    xs[rr][d] = allemb[(r0 + rr) * 128 + d];
    as[rr][d] = atten[(r0 + rr) * 128 + d];
  }
  __syncthreads();
  const int j = tid & 127, h = tid >> 7;
  const float fbj = fb[j];
  float acc1[4], acc2[4];
#pragma unroll
  for (int r = 0; r < 4; ++r) { acc1[r] = fbj; acc2[r] = fbj; }
  for (int d = 0; d < 128; d += 4) {
    const float w0 = fwdT[(d + 0) * 128 + j];
    const float w1 = fwdT[(d + 1) * 128 + j];
    const float w2 = fwdT[(d + 2) * 128 + j];
    const float w3 = fwdT[(d + 3) * 128 + j];
#pragma unroll
    for (int r = 0; r < 4; ++r) {
      const int rr = h * 4 + r;
      const float4 xv = *(const float4*)&xs[rr][d];
      const float4 av = *(const float4*)&as[rr][d];
      acc1[r] += xv.x * w0 + xv.y * w1 + xv.z * w2 + xv.w * w3;
      acc2[r] += av.x * w0 + av.y * w1 + av.z * w2 + av.w * w3;
    }
  }
  float ls1 = 0.f, ls2 = 0.f;
#pragma unroll
  for (int r = 0; r < 4; ++r) {
    const int rr = h * 4 + r;
    const float t1 = tanhf(acc1[r]);
    const float t2 = tanhf(acc2[r]);
    z1[(r0 + rr) * 128 + j] = t1;
    z2[(r0 + rr) * 128 + j] = t2;
    ls1 += expf(t1 - 1.0f);
    ls2 += expf(t2 - 1.0f);
  }
  red1[h][j] = ls1;
  red2[h][j] = ls2;
  __syncthreads();
  if (h == 0) {
    const int rep = blockIdx.x & 15;
    atomicAdd(&cs1[rep * 128 + j], red1[0][j] + red1[1][j]);
    atomicAdd(&cs2[rep * 128 + j], red2[0][j] + red2[1][j]);
  }
}

__global__ void k_fuse2(const float* __restrict__ allemb, const float* __restrict__ atten,
                        const float* __restrict__ z1, const float* __restrict__ z2,
                        const float* __restrict__ cs1, const float* __restrict__ cs2,
                        float* __restrict__ fusion) {
  __shared__ float s1[128], s2[128];
  const int tid = threadIdx.x;
  if (tid < 128) {
    float a = 0.f, b = 0.f;
#pragma unroll
    for (int rep = 0; rep < 16; ++rep) {
      a += cs1[rep * 128 + tid];
      b += cs2[rep * 128 + tid];
    }
    s1[tid] = a; s2[tid] = b;
  }
  __syncthreads();
  const int i = blockIdx.x * 256 + tid;
  const int j = i & 127;
  const float a1 = expf(z1[i] - 1.0f) / s1[j];
  const float a2 = expf(z2[i] - 1.0f) / s2[j];
  fusion[i] = a1 * allemb[i] + a2 * atten[i];
}

// ---------------------------------------------------------------- launch ----
extern "C" void kernel_launch(void* const* d_in, const int* in_sizes, int n_in,
                              void* d_out, int out_size, void* d_ws, size_t ws_size,
                              hipStream_t stream) {
  (void)in_sizes; (void)n_in; (void)out_size; (void)ws_size;
  const float* user = (const float*)d_in[0];
  const float* item = (const float*)d_in[1];
  const int* adj_rows = (const int*)d_in[2];
  const int* adj_cols = (const int*)d_in[3];
  const float* adj_vals = (const float*)d_in[4];
  const float* wq = (const float*)d_in[5];
  const float* bq = (const float*)d_in[6];
  const float* wk = (const float*)d_in[7];
  const float* wv = (const float*)d_in[9];
  const float* bv = (const float*)d_in[10];
  const float* fw = (const float*)d_in[11];
  const float* fb = (const float*)d_in[12];

  float* out = (float*)d_out;
  float* allemb = out;                    // [N,D]
  float* atten = out + (size_t)N_ * D_;   // [N,D]
  float* fusion = out + (size_t)2 * N_ * D_;

  char* ws = (char*)d_ws;
  size_t off = 0;
  auto alloc = [&](size_t bytes) { char* p = ws + off; off += (bytes + 255) & ~(size_t)255; return p; };
  float* ego_a = (float*)alloc((size_t)N_ * D_ * 4);
  float* ego_b = (float*)alloc((size_t)N_ * D_ * 4);
  float* qkbuf = (float*)alloc((size_t)N_ * D_ * 4);
  u16* Gh = (u16*)alloc((size_t)N_ * D_ * 2);
  u16* Gl = (u16*)alloc((size_t)N_ * D_ * 2);
  u16* XTh = (u16*)alloc((size_t)N_ * D_ * 2);
  u16* XTl = (u16*)alloc((size_t)N_ * D_ * 2);
  int2* gbuf = (int2*)alloc((size_t)N_ * CAP_ * 8);  // (col,val) pairs (aliased by z1)
  float* z1 = (float*)gbuf;                          // lifetimes disjoint
  float* z2 = (float*)alloc((size_t)N_ * D_ * 4);
  int* topk_idx = (int*)alloc((size_t)N_ * 32 * 4);
  int* ccol = (int*)alloc((size_t)E_ * 4);
  float* cval = (float*)alloc((size_t)E_ * 4);
  int* cnt = (int*)alloc((size_t)N_ * 4);
  int* row_ptr = (int*)alloc((size_t)(N_ + 1) * 4);
  int* cursor = (int*)alloc((size_t)N_ * 4);
  float* M = (float*)alloc(128 * 128 * 4);
  float* bqk = (float*)alloc(128 * 4);
  float* wvT = (float*)alloc(128 * 128 * 4);
  float* fwdT = (float*)alloc(128 * 128 * 4);
  float* cs1 = (float*)alloc(16 * 128 * 4);           // 16 replicas
  float* cs2 = (float*)alloc(16 * 128 * 4);
  float* C2 = (float*)alloc(128 * 128 * 4);
  float* C2part = (float*)alloc((size_t)256 * 16384 * 4);   // 16 MB partials
  float* svec = (float*)alloc(128 * 4);
  float* tau = (float*)alloc((size_t)N_ * 4);
  int* gcount = (int*)alloc((size_t)N_ * 4);          // legacy (unused by hot path)
  int* gstripcnt = (int*)alloc((size_t)N_ * 16 * 4);  // per (row,strip) counts
  int* failq = (int*)alloc(64 * 4);
  int* failn = (int*)alloc(4);
  double* fsim = (double*)alloc((size_t)64 * N_ * 8);

  k_init<<<64, 256, 0, stream>>>(wq, wk, bq, wv, fw, M, bqk, wvT, fwdT, cnt, cs1, cs2, svec, gcount, failn);
  k_concat<<<8192, 256, 0, stream>>>(user, item, ego_a);
  k_hist<<<2048, 256, 0, stream>>>(adj_rows, cnt);
  k_scan<<<1, 1024, 0, stream>>>(cnt, row_ptr, cursor);
  k_scatter<<<2048, 256, 0, stream>>>(adj_rows, adj_cols, adj_vals, cursor, ccol, cval);

  k_spmm<<<N_, 128, 0, stream>>>(ego_a, ego_b, allemb, row_ptr, ccol, cval, 1);
  k_spmm<<<N_, 128, 0, stream>>>(ego_b, ego_a, allemb, row_ptr, ccol, cval, 0);
  k_spmm<<<N_, 128, 0, stream>>>(ego_a, ego_b, allemb, row_ptr, ccol, cval, 0);
  // ego3 = ego_b
  k_div3<<<8192, 256, 0, stream>>>(allemb);

  k_split_t<<<256, 256, 0, stream>>>(ego_b, Gh, Gl, XTh, XTl, svec);
  k_c2mfma<<<256, 256, 0, stream>>>(XTh, XTl, C2part);
  k_c2red<<<64, 256, 0, stream>>>(C2part, C2);
  k_tau<<<N_, 128, 0, stream>>>(ego_b, C2, svec, tau);

  k_qk<<<2048, 256, 0, stream>>>(ego_b, M, bqk, qkbuf);
  k_simmfma<<<2048, 256, 0, stream>>>(Gh, Gl, tau, gstripcnt, gbuf);   // round-6 cfg + gload_lds
  k_check<<<64, 256, 0, stream>>>(gstripcnt, failq, failn);
  k_refine<<<4096, 256, 0, stream>>>(gstripcnt, gbuf, topk_idx);
  k_fallback<<<64, 256, 0, stream>>>(ego_b, failq, failn, fsim, topk_idx);
  k_attn<<<N_, 128, 0, stream>>>(ego_b, qkbuf, topk_idx, wvT, bv, atten);

  k_fuse1<<<2048, 256, 0, stream>>>(allemb, atten, fwdT, fb, z1, z2, cs1, cs2);
  k_fuse2<<<8192, 256, 0, stream>>>(allemb, atten, z1, z2, cs1, cs2, fusion);
}

// Round 9
// 687.145 us; speedup vs baseline: 2.1103x; 1.1453x over previous
//
#include <hip/hip_runtime.h>
#include <math.h>

#define U_ 8192
#define I_ 8192
#define D_ 128
#define E_ 524288
#define N_ 16384
#define K_ 32
#define CAP_ 512

typedef unsigned short u16;
typedef unsigned int u32;
typedef unsigned long long u64;
typedef __attribute__((ext_vector_type(8))) short bf16x8;
typedef __attribute__((ext_vector_type(4))) float f32x4;

// ---------------------------------------------------------------- init ------
__global__ void k_init(const float* __restrict__ wq, const float* __restrict__ wk,
                       const float* __restrict__ bq, const float* __restrict__ wv,
                       const float* __restrict__ fw,
                       float* __restrict__ M, float* __restrict__ bqk,
                       float* __restrict__ wvT, float* __restrict__ fwdT,
                       int* __restrict__ cnt, float* __restrict__ cs1,
                       float* __restrict__ cs2,
                       float* __restrict__ svec, int* __restrict__ gcount,
                       int* __restrict__ failn) {
  const int tid = blockIdx.x * 256 + threadIdx.x;   // 64 blocks -> 16384 threads
  cnt[tid] = 0;
  gcount[tid] = 0;
  if (tid < 2048) { cs1[tid] = 0.f; cs2[tid] = 0.f; }   // 16 replicas x 128
  if (tid < 128) svec[tid] = 0.f;
  if (tid == 0) *failn = 0;
  // M[i][j] = sum_l wq[l,i]*wk[l,j]  (wq^T wk)
  const int i = tid >> 7, j = tid & 127;
  float s = 0.f;
  for (int l = 0; l < 128; ++l) s += wq[l * 128 + i] * wk[l * 128 + j];
  M[tid] = s;
  wvT[i * 128 + j] = wv[j * 128 + i];
  fwdT[i * 128 + j] = fw[j * 128 + i];   // fwdT[d][j] = fw[j][d] (d-major)
  if (tid < 128) {
    float s2 = 0.f;
    for (int l = 0; l < 128; ++l) s2 += bq[l] * wk[l * 128 + tid];
    bqk[tid] = s2;
  }
}

__global__ void k_concat(const float* __restrict__ user, const float* __restrict__ item,
                         float* __restrict__ ego) {
  const int i = blockIdx.x * 256 + threadIdx.x;     // 8192 blocks, exact
  ego[i] = (i < U_ * D_) ? user[i] : item[i - U_ * D_];
}

// ---------------------------------------------------------------- CSR -------
__global__ void k_hist(const int* __restrict__ rows, int* __restrict__ cnt) {
  const int e = blockIdx.x * 256 + threadIdx.x;     // 2048 blocks, exact
  atomicAdd(&cnt[rows[e]], 1);
}

// wave-scan: shfl_up intra-wave + 16-partial scan; 4 barriers/chunk.
__global__ void k_scan(const int* __restrict__ cnt, int* __restrict__ row_ptr,
                       int* __restrict__ cursor) {
  __shared__ int wsum[16];
  __shared__ int carry_s;
  const int t = threadIdx.x;                 // 1024 threads
  const int lane = t & 63, wid = t >> 6;
  if (t == 0) carry_s = 0;
  __syncthreads();
  for (int c = 0; c < N_ / 1024; ++c) {
    const int x = cnt[c * 1024 + t];
    int incl = x;
#pragma unroll
    for (int off = 1; off < 64; off <<= 1) {
      const int v = __shfl_up(incl, off, 64);
      if (lane >= off) incl += v;
    }
    if (lane == 63) wsum[wid] = incl;
    __syncthreads();
    if (wid == 0) {
      int s = (lane < 16) ? wsum[lane] : 0;
#pragma unroll
      for (int off = 1; off < 16; off <<= 1) {
        const int v = __shfl_up(s, off, 64);
        if (lane >= off) s += v;
      }
      if (lane < 16) wsum[lane] = s;
    }
    __syncthreads();
    const int carry = carry_s;
    const int wbase = wid ? wsum[wid - 1] : 0;
    const int excl = carry + wbase + incl - x;
    row_ptr[c * 1024 + t] = excl;
    cursor[c * 1024 + t] = excl;
    __syncthreads();
    if (t == 1023) carry_s += wsum[15];
    __syncthreads();
  }
  if (t == 0) row_ptr[N_] = carry_s;
}

__global__ void k_scatter(const int* __restrict__ rows, const int* __restrict__ cols,
                          const float* __restrict__ vals, int* __restrict__ cursor,
                          int* __restrict__ ccol, float* __restrict__ cval) {
  const int e = blockIdx.x * 256 + threadIdx.x;
  const int r = rows[e];
  const int p = atomicAdd(&cursor[r], 1);
  ccol[p] = cols[e];
  cval[p] = vals[e];
}

// ---------------------------------------------------------------- SpMM ------
// v2: 4 independent double accumulators (breaks the dependent-FMA chain,
// keeps 4 gathers in flight); `last` folds the /3 (k_div3 removed).
__global__ __launch_bounds__(128) void k_spmm(const float* __restrict__ x,
                                              float* __restrict__ y,
                                              float* __restrict__ sum,
                                              const int* __restrict__ row_ptr,
                                              const int* __restrict__ ccol,
                                              const float* __restrict__ cval,
                                              const int first, const int last) {
  const int r = blockIdx.x, d = threadIdx.x;
  const int b = row_ptr[r], e = row_ptr[r + 1];
  double a0 = 0.0, a1 = 0.0, a2 = 0.0, a3 = 0.0;
  int i = b;
  for (; i + 3 < e; i += 4) {
    a0 += (double)cval[i + 0] * (double)x[ccol[i + 0] * 128 + d];
    a1 += (double)cval[i + 1] * (double)x[ccol[i + 1] * 128 + d];
    a2 += (double)cval[i + 2] * (double)x[ccol[i + 2] * 128 + d];
    a3 += (double)cval[i + 3] * (double)x[ccol[i + 3] * 128 + d];
  }
  for (; i < e; ++i)
    a0 += (double)cval[i] * (double)x[ccol[i] * 128 + d];
  const float f = (float)((a0 + a1) + (a2 + a3));
  y[r * 128 + d] = f;
  float s = first ? f : sum[r * 128 + d] + f;
  if (last) s = s / 3.0f;
  sum[r * 128 + d] = s;
}

// ------------------------------------------------- split + transpose --------
__global__ __launch_bounds__(256) void k_split_t(const float* __restrict__ x,
                                                 u16* __restrict__ Gh, u16* __restrict__ Gl,
                                                 u16* __restrict__ XTh, u16* __restrict__ XTl,
                                                 float* __restrict__ svec) {
  __shared__ u16 lh[128 * 66];
  __shared__ u16 ll[128 * 66];
  const int tid = threadIdx.x;
  const int r0 = blockIdx.x * 64;
  float colsum = 0.f;
  for (int s = 0; s < 32; ++s) {
    const int idx = tid + s * 256;
    const int r = idx >> 7, d = idx & 127;
    const float v = x[(r0 + r) * 128 + d];
    colsum += v;
    unsigned int u = __float_as_uint(v);
    u += 0x7fffu + ((u >> 16) & 1u);
    const u16 h = (u16)(u >> 16);
    const float hf = __uint_as_float(((unsigned int)h) << 16);
    const float l = v - hf;
    unsigned int u2 = __float_as_uint(l);
    u2 += 0x7fffu + ((u2 >> 16) & 1u);
    const u16 lo = (u16)(u2 >> 16);
    Gh[(r0 + r) * 128 + d] = h;
    Gl[(r0 + r) * 128 + d] = lo;
    lh[d * 66 + r] = h;
    ll[d * 66 + r] = lo;
  }
  atomicAdd(&svec[tid & 127], colsum);
  __syncthreads();
  for (int s = 0; s < 32; ++s) {
    const int idx = tid + s * 256;
    const int d = idx >> 6, rr = idx & 63;
    XTh[d * 16384 + r0 + rr] = lh[d * 66 + rr];
    XTl[d * 16384 + r0 + rr] = ll[d * 66 + rr];
  }
}

// ---------------------------------------------------------------- C2 --------
// v2 (kept): 256 blocks, disjoint-element partials to private slabs; no atomics.
__global__ __launch_bounds__(256) void k_c2mfma(const u16* __restrict__ XTh,
                                                const u16* __restrict__ XTl,
                                                float* __restrict__ C2part) {
  const int tid = threadIdx.x, w = tid >> 6, lane = tid & 63;
  const int n16 = lane & 15, kq = lane >> 4;
  const int c0 = blockIdx.x * 64;
  f32x4 acc[2][8];
#pragma unroll
  for (int a = 0; a < 2; ++a)
#pragma unroll
    for (int b = 0; b < 8; ++b) acc[a][b] = (f32x4){0.f, 0.f, 0.f, 0.f};
  for (int ks = 0; ks < 2; ++ks) {
    const int c = c0 + ks * 32 + kq * 8;
    bf16x8 Fh[8], Fl[8];
#pragma unroll
    for (int g = 0; g < 8; ++g) {
      const int base = (g * 16 + n16) * 16384 + c;
      Fh[g] = *(const bf16x8*)&XTh[base];
      Fl[g] = *(const bf16x8*)&XTl[base];
    }
#pragma unroll
    for (int a = 0; a < 2; ++a) {
      const int tr = w * 2 + a;
#pragma unroll
      for (int b = 0; b < 8; ++b) {
        acc[a][b] = __builtin_amdgcn_mfma_f32_16x16x32_bf16(Fl[tr], Fh[b], acc[a][b], 0, 0, 0);
        acc[a][b] = __builtin_amdgcn_mfma_f32_16x16x32_bf16(Fh[tr], Fl[b], acc[a][b], 0, 0, 0);
        acc[a][b] = __builtin_amdgcn_mfma_f32_16x16x32_bf16(Fh[tr], Fh[b], acc[a][b], 0, 0, 0);
      }
    }
  }
  float* dst = C2part + (size_t)blockIdx.x * 16384;
#pragma unroll
  for (int a = 0; a < 2; ++a) {
    const int tr = w * 2 + a;
#pragma unroll
    for (int b = 0; b < 8; ++b)
#pragma unroll
      for (int i = 0; i < 4; ++i)
        dst[(tr * 16 + kq * 4 + i) * 128 + b * 16 + n16] = acc[a][b][i];
  }
}

__global__ void k_c2red(const float* __restrict__ C2part, float* __restrict__ C2) {
  const int e = blockIdx.x * 256 + threadIdx.x;   // 64 blocks -> 16384
  float s = 0.f;
  for (int b = 0; b < 256; ++b) s += C2part[(size_t)b * 16384 + e];
  C2[e] = s;
}

// ---------------------------------------------------------------- tau -------
// v2: thin-tile -- 8 rows/block (2048 blocks) so C2 (64KB) is read once per
// block instead of once per row: L2 traffic 1GB -> 128MB, and the 8
// independent per-row dot chains give ILP over the dependent double-FMA.
// Per-row arithmetic order identical to v1 -> bit-identical tau.
__global__ __launch_bounds__(128) void k_tau(const float* __restrict__ x,
                                             const float* __restrict__ C2,
                                             const float* __restrict__ svec,
                                             float* __restrict__ tau) {
  __shared__ float xs[8][128];
  __shared__ double red[128];
  const int tid = threadIdx.x;
  const int n0 = blockIdx.x * 8;
#pragma unroll
  for (int rr = 0; rr < 8; ++rr) xs[rr][tid] = x[(n0 + rr) * 128 + tid];
  __syncthreads();
  double y[8];
#pragma unroll
  for (int rr = 0; rr < 8; ++rr) y[rr] = 0.0;
  for (int k2 = 0; k2 < 128; ++k2) {
    const double c = (double)C2[k2 * 128 + tid];
#pragma unroll
    for (int rr = 0; rr < 8; ++rr) y[rr] += (double)xs[rr][k2] * c;
  }
  const double sv = (double)svec[tid];
  for (int rr = 0; rr < 8; ++rr) {
    red[tid] = (double)xs[rr][tid] * y[rr];
    __syncthreads();
    for (int s = 64; s; s >>= 1) { if (tid < s) red[tid] += red[tid + s]; __syncthreads(); }
    const double exy = red[0] / 16384.0;
    __syncthreads();
    red[tid] = (double)xs[rr][tid] * sv;
    __syncthreads();
    for (int s = 64; s; s >>= 1) { if (tid < s) red[tid] += red[tid + s]; __syncthreads(); }
    if (tid == 0) {
      const double m = red[0] / 16384.0;
      double var = exy - m * m;
      if (var < 0.0) var = 0.0;
      tau[n0 + rr] = (float)(m + 2.55 * sqrt(var));
    }
    __syncthreads();
  }
}

// ---------------------------------------------------------------- qk --------
// v2: thin-tile matmul, 2048 blocks x 256 threads, 8 rows/block in 4KB LDS.
__global__ __launch_bounds__(256) void k_qk(const float* __restrict__ ego,
                                            const float* __restrict__ M,
                                            const float* __restrict__ bqk,
                                            float* __restrict__ qkout) {
  __shared__ float xs[8][128];
  const int tid = threadIdx.x;
  const int r0 = blockIdx.x * 8;
#pragma unroll
  for (int s = 0; s < 4; ++s) {
    const int idx = tid + s * 256;
    xs[idx >> 7][idx & 127] = ego[r0 * 128 + idx];
  }
  __syncthreads();
  const int j = tid & 127, h = tid >> 7;
  const float bj = bqk[j];
  float acc[4];
#pragma unroll
  for (int r = 0; r < 4; ++r) acc[r] = bj;
  for (int d = 0; d < 128; d += 4) {
    const float w0 = M[(d + 0) * 128 + j];
    const float w1 = M[(d + 1) * 128 + j];
    const float w2 = M[(d + 2) * 128 + j];
    const float w3 = M[(d + 3) * 128 + j];
#pragma unroll
    for (int r = 0; r < 4; ++r) {
      const float4 xv = *(const float4*)&xs[h * 4 + r][d];
      acc[r] += xv.x * w0 + xv.y * w1 + xv.z * w2 + xv.w * w3;
    }
  }
#pragma unroll
  for (int r = 0; r < 4; ++r)
    qkout[(r0 + h * 4 + r) * 128 + j] = acc[r];
}

// ------------------------------------------------------- sim via MFMA -------
// Round-8 winner, untouched: round-6 cfg + swizzled global_load_lds staging.
__device__ __forceinline__ void gload_lds16(const u16* g, u16* l) {
  __builtin_amdgcn_global_load_lds(
      (const __attribute__((address_space(1))) void*)g,
      (__attribute__((address_space(3))) void*)l, 16, 0, 0);
}

__global__ __launch_bounds__(256) void k_simmfma(const u16* __restrict__ Gh,
                                                 const u16* __restrict__ Gl,
                                                 const float* __restrict__ tau,
                                                 int* __restrict__ gstripcnt,
                                                 int2* __restrict__ gbuf) {
  __shared__ __align__(16) u16 lh[64 * 128];   // 16 KB, linear 256-B rows
  __shared__ int cnt128[128];
  const int tid = threadIdx.x;
  const int w = tid >> 6, lane = tid & 63;
  const int strip = blockIdx.x & 15, rgrp = blockIdx.x >> 4;
  const int n16 = lane & 15, kq = lane >> 4;

  if (tid < 128) cnt128[tid] = 0;

  const int rowbase = rgrp * 128 + w * 32;
  bf16x8 Bh[2][4], Bl[2][4];
#pragma unroll
  for (int rg = 0; rg < 2; ++rg) {
    const int row = rowbase + rg * 16 + n16;
#pragma unroll
    for (int q = 0; q < 4; ++q) {
      Bh[rg][q] = *(const bf16x8*)&Gh[row * 128 + q * 32 + kq * 8];
      Bl[rg][q] = *(const bf16x8*)&Gl[row * 128 + q * 32 + kq * 8];
    }
  }
  const float tau0 = tau[rowbase + n16];
  const float tau1 = tau[rowbase + 16 + n16];
  const int col0 = strip * 1024;

  for (int st = 0; st < 16; ++st) {
    const int cb = col0 + st * 64;
    __syncthreads();
#pragma unroll
    for (int ii = 0; ii < 4; ++ii) {
      const int srow = w * 16 + ii * 4 + kq;
      const int chunk = n16 ^ (srow & 7);
      gload_lds16(Gh + (((size_t)(cb + srow)) << 7) + chunk * 8,
                  lh + ((w * 16 + ii * 4) << 7));
    }
    __syncthreads();   // drains vmcnt: staged tile visible to all waves
#pragma unroll
    for (int ct = 0; ct < 4; ++ct) {
      const int ar = ct * 16 + n16;
      const char* lbase = (const char*)lh + ar * 256;
      bf16x8 Ah[4];
#pragma unroll
      for (int q = 0; q < 4; ++q)
        Ah[q] = *(const bf16x8*)(lbase + ((q * 64 + kq * 16) ^ ((ar & 7) << 4)));
#pragma unroll
      for (int rg = 0; rg < 2; ++rg) {
        f32x4 p = {0.f, 0.f, 0.f, 0.f};
        f32x4 r = {0.f, 0.f, 0.f, 0.f};
#pragma unroll
        for (int q = 0; q < 4; ++q) {
          p = __builtin_amdgcn_mfma_f32_16x16x32_bf16(Ah[q], Bh[rg][q], p, 0, 0, 0);
          r = __builtin_amdgcn_mfma_f32_16x16x32_bf16(Ah[q], Bl[rg][q], r, 0, 0, 0);
        }
        const float tv = rg ? tau1 : tau0;
        const int lrow = w * 32 + rg * 16 + n16;     // block-local row 0..127
        const int row = rgrp * 128 + lrow;
#pragma unroll
        for (int i = 0; i < 4; ++i) {
          const float v = p[i] + r[i];
          if (v > tv) {
            const int c = cb + ct * 16 + kq * 4 + i;
            const int pos = atomicAdd(&cnt128[lrow], 1);   // LDS atomic
            if (pos < 32)
              gbuf[row * CAP_ + strip * 32 + pos] = make_int2(c, __float_as_int(v));
          }
        }
      }
    }
  }
  __syncthreads();
  if (tid < 128) gstripcnt[(rgrp * 128 + tid) * 16 + strip] = cnt128[tid];
}

// rows whose candidate counts violate {total in [36,CAP_], every strip<=32}
// go to the exact fallback
__global__ void k_check(const int* __restrict__ gstripcnt, int* __restrict__ failq,
                        int* __restrict__ failn) {
  const int n = blockIdx.x * 256 + threadIdx.x;   // 64 blocks
  int total = 0; int over = 0;
#pragma unroll
  for (int s = 0; s < 16; ++s) {
    const int c = gstripcnt[n * 16 + s];
    total += c;
    over |= (c > 32);
  }
  if (total < 36 || total > CAP_ || over) {
    const int s = atomicAdd(failn, 1);
    if (s < 64) failq[s] = n;
  }
}

// Top-32 by stored fp32 sim values via RANK-SCATTER on packed u64 keys:
// key = (sortable_f32 << 32) | (16383 - col)  -> (val desc, col asc) order.
__global__ __launch_bounds__(256) void k_refine(const int* __restrict__ gstripcnt,
                                                const int2* __restrict__ gbuf,
                                                int* __restrict__ topk_idx) {
  __shared__ u64 lk[4][CAP_];
  const int tid = threadIdx.x, w = tid >> 6, lane = tid & 63;
  const int n = blockIdx.x * 4 + w;

  const int scn = (lane < 16) ? gstripcnt[n * 16 + lane] : 0;
  int total = 0, over = 0;
#pragma unroll
  for (int s = 0; s < 16; ++s) {
    const int c = __shfl(scn, s, 64);
    total += c;
    over |= (c > 32);
  }
  const int bad = (total < 36 || total > CAP_ || over);
  const int cnt = bad ? 0 : total;

  // compact the 16 segments into lk[w][0..cnt)
  int base = 0;
#pragma unroll
  for (int s = 0; s < 16; ++s) {
    const int c = __shfl(scn, s, 64);
    if (!bad && lane < c) {
      const int2 p = gbuf[n * CAP_ + s * 32 + lane];
      u32 uv = (u32)p.y;
      uv = (uv >> 31) ? ~uv : (uv | 0x80000000u);
      lk[w][base + lane] = ((u64)uv << 32) | (u64)(16383 - p.x);
    }
    base += bad ? 0 : c;
  }
  __syncthreads();

  for (int ci = lane; ci < cnt; ci += 64) {
    const u64 kk = lk[w][ci];
    int r = 0;
#pragma unroll 4
    for (int j = 0; j < cnt; ++j)
      r += (lk[w][j] > kk) ? 1 : 0;
    if (r < 32) topk_idx[n * 32 + r] = 16383 - (int)(u32)(kk & 0xffffffffu);
  }
  if (bad && lane < 32) topk_idx[n * 32 + lane] = 0;  // placeholder; fallback overwrites
}

// exact fp64 full-row top-32 for statistically-failed rows (expected: none)
__global__ __launch_bounds__(256) void k_fallback(const float* __restrict__ x,
                                                  const int* __restrict__ failq,
                                                  const int* __restrict__ failn,
                                                  double* __restrict__ fsim,
                                                  int* __restrict__ topk_idx) {
  const int nf = *failn;
  const int which = blockIdx.x;
  if (which >= nf || which >= 64) return;
  const int row = failq[which];
  __shared__ float xs[128];
  __shared__ double bm[256];
  __shared__ int bc[256];
  const int tid = threadIdx.x;
  if (tid < 128) xs[tid] = x[row * 128 + tid];
  __syncthreads();
  double* fs = fsim + (size_t)which * 16384;
  for (int c = tid; c < 16384; c += 256) {
    const float4* xp = (const float4*)&x[c * 128];
    double a = 0.0;
    for (int d = 0; d < 32; ++d) {
      const float4 v = xp[d];
      a += (double)xs[d * 4 + 0] * (double)v.x + (double)xs[d * 4 + 1] * (double)v.y +
           (double)xs[d * 4 + 2] * (double)v.z + (double)xs[d * 4 + 3] * (double)v.w;
    }
    fs[c] = a;
  }
  __syncthreads();
  for (int r = 0; r < 32; ++r) {
    double m = -1.0e300; int mc = 0;
    for (int c = tid; c < 16384; c += 256) {
      const double v = fs[c];
      if (v > m || (v == m && c < mc)) { m = v; mc = c; }
    }
    bm[tid] = m; bc[tid] = mc;
    __syncthreads();
    for (int s = 128; s; s >>= 1) {
      if (tid < s) {
        if (bm[tid + s] > bm[tid] || (bm[tid + s] == bm[tid] && bc[tid + s] < bc[tid])) {
          bm[tid] = bm[tid + s]; bc[tid] = bc[tid + s];
        }
      }
      __syncthreads();
    }
    if (tid == 0) { topk_idx[row * 32 + r] = bc[0]; fs[bc[0]] = -1.0e300; }
    __syncthreads();
  }
}

// ------------------------------------------------------- attention ----------
// v2: ends at sa (weighted sample sum), written IN PLACE into qkbuf (block n
// owns row n; qv already consumed).  The linear wvT projection + bv + 0.1*ego
// moves to the thin-tile k_attnmm, amortizing the 64KB wvT across 8 rows
// (L2 traffic 1GB -> 128MB) -- same disease/fix as round-4's fuse1.
__global__ __launch_bounds__(128) void k_attn(const float* __restrict__ ego,
                                              float* __restrict__ qk,
                                              const int* __restrict__ topk_idx) {
  __shared__ float qv[128];
  __shared__ float sm[32 * 129];
  __shared__ int tki[32];
  __shared__ float sc[32];
  __shared__ float psum[128];
  const int n = blockIdx.x, tid = threadIdx.x;
  qv[tid] = qk[n * 128 + tid];
  if (tid < 32) tki[tid] = topk_idx[n * 32 + tid] & 16383;
  __syncthreads();
  for (int e = tid; e < 32 * 128; e += 128) {
    const int k2 = e >> 7, d = e & 127;
    sm[k2 * 129 + d] = ego[tki[k2] * 128 + d];
  }
  __syncthreads();
  {
    const int kk = tid & 31, part = tid >> 5;
    float s = 0.f;
    const int d0 = part * 32;
    for (int d = d0; d < d0 + 32; ++d) s += qv[d] * sm[kk * 129 + d];
    psum[tid] = s;
  }
  __syncthreads();
  if (tid < 32) {
    float v = psum[tid] + psum[tid + 32] + psum[tid + 64] + psum[tid + 96];
    v *= (1.0f / 11.313708498984760f);    // 1/sqrt(128)
    float m = v;
#pragma unroll
    for (int off = 16; off; off >>= 1) m = fmaxf(m, __shfl_xor(m, off, 32));
    const float e = expf(v - m);
    float ssum = e;
#pragma unroll
    for (int off = 16; off; off >>= 1) ssum += __shfl_xor(ssum, off, 32);
    sc[tid] = e / ssum;
  }
  __syncthreads();
  float sad = 0.f;
  for (int k2 = 0; k2 < 32; ++k2) sad += sc[k2] * sm[k2 * 129 + tid];
  qk[n * 128 + tid] = sad;            // sa, in place (qv fully consumed)
}

// thin-tile: atten = sa @ wvT + bv + 0.1*ego.  8 rows/block, 2048 blocks.
__global__ __launch_bounds__(256) void k_attnmm(const float* __restrict__ sa,
                                                const float* __restrict__ ego,
                                                const float* __restrict__ wvT,
                                                const float* __restrict__ bv,
                                                float* __restrict__ atten) {
  __shared__ float xs[8][128];
  const int tid = threadIdx.x;
  const int r0 = blockIdx.x * 8;
#pragma unroll
  for (int s = 0; s < 4; ++s) {
    const int idx = tid + s * 256;
    xs[idx >> 7][idx & 127] = sa[r0 * 128 + idx];
  }
  __syncthreads();
  const int j = tid & 127, h = tid >> 7;
  const float bj = bv[j];
  float acc[4];
#pragma unroll
  for (int r = 0; r < 4; ++r) acc[r] = bj;
  for (int d = 0; d < 128; d += 4) {
    const float w0 = wvT[(d + 0) * 128 + j];
    const float w1 = wvT[(d + 1) * 128 + j];
    const float w2 = wvT[(d + 2) * 128 + j];
    const float w3 = wvT[(d + 3) * 128 + j];
#pragma unroll
    for (int r = 0; r < 4; ++r) {
      const float4 xv = *(const float4*)&xs[h * 4 + r][d];
      acc[r] += xv.x * w0 + xv.y * w1 + xv.z * w2 + xv.w * w3;
    }
  }
#pragma unroll
  for (int r = 0; r < 4; ++r) {
    const int n = r0 + h * 4 + r;
    atten[n * 128 + j] = acc[r] + 0.1f * ego[n * 128 + j];
  }
}

// ------------------------------------------------------- fusion -------------
__global__ __launch_bounds__(256) void k_fuse1(const float* __restrict__ allemb,
                                               const float* __restrict__ atten,
                                               const float* __restrict__ fwdT,
                                               const float* __restrict__ fb,
                                               float* __restrict__ z1,
                                               float* __restrict__ z2,
                                               float* __restrict__ cs1,
                                               float* __restrict__ cs2) {
  __shared__ float xs[8][128];
  __shared__ float as[8][128];
  __shared__ float red1[2][128];
  __shared__ float red2[2][128];
  const int tid = threadIdx.x;
  const int r0 = blockIdx.x * 8;
#pragma unroll
  for (int s = 0; s < 4; ++s) {
    const int idx = tid + s * 256;
    const int rr = idx >> 7, d = idx & 127;
    xs[rr][d] = allemb[(r0 + rr) * 128 + d];
    as[rr][d] = atten[(r0 + rr) * 128 + d];
  }
  __syncthreads();
  const int j = tid & 127, h = tid >> 7;
  const float fbj = fb[j];
  float acc1[4], acc2[4];
#pragma unroll
  for (int r = 0; r < 4; ++r) { acc1[r] = fbj; acc2[r] = fbj; }
  for (int d = 0; d < 128; d += 4) {
    const float w0 = fwdT[(d + 0) * 128 + j];
    const float w1 = fwdT[(d + 1) * 128 + j];
    const float w2 = fwdT[(d + 2) * 128 + j];
    const float w3 = fwdT[(d + 3) * 128 + j];
#pragma unroll
    for (int r = 0; r < 4; ++r) {
      const int rr = h * 4 + r;
      const float4 xv = *(const float4*)&xs[rr][d];
      const float4 av = *(const float4*)&as[rr][d];
      acc1[r] += xv.x * w0 + xv.y * w1 + xv.z * w2 + xv.w * w3;
      acc2[r] += av.x * w0 + av.y * w1 + av.z * w2 + av.w * w3;
    }
  }
  float ls1 = 0.f, ls2 = 0.f;
#pragma unroll
  for (int r = 0; r < 4; ++r) {
    const int rr = h * 4 + r;
    const float t1 = tanhf(acc1[r]);
    const float t2 = tanhf(acc2[r]);
    z1[(r0 + rr) * 128 + j] = t1;
    z2[(r0 + rr) * 128 + j] = t2;
    ls1 += expf(t1 - 1.0f);
    ls2 += expf(t2 - 1.0f);
  }
  red1[h][j] = ls1;
  red2[h][j] = ls2;
  __syncthreads();
  if (h == 0) {
    const int rep = blockIdx.x & 15;
    atomicAdd(&cs1[rep * 128 + j], red1[0][j] + red1[1][j]);
    atomicAdd(&cs2[rep * 128 + j], red2[0][j] + red2[1][j]);
  }
}

__global__ void k_fuse2(const float* __restrict__ allemb, const float* __restrict__ atten,
                        const float* __restrict__ z1, const float* __restrict__ z2,
                        const float* __restrict__ cs1, const float* __restrict__ cs2,
                        float* __restrict__ fusion) {
  __shared__ float s1[128], s2[128];
  const int tid = threadIdx.x;
  if (tid < 128) {
    float a = 0.f, b = 0.f;
#pragma unroll
    for (int rep = 0; rep < 16; ++rep) {
      a += cs1[rep * 128 + tid];
      b += cs2[rep * 128 + tid];
    }
    s1[tid] = a; s2[tid] = b;
  }
  __syncthreads();
  const int i = blockIdx.x * 256 + tid;
  const int j = i & 127;
  const float a1 = expf(z1[i] - 1.0f) / s1[j];
  const float a2 = expf(z2[i] - 1.0f) / s2[j];
  fusion[i] = a1 * allemb[i] + a2 * atten[i];
}

// ---------------------------------------------------------------- launch ----
extern "C" void kernel_launch(void* const* d_in, const int* in_sizes, int n_in,
                              void* d_out, int out_size, void* d_ws, size_t ws_size,
                              hipStream_t stream) {
  (void)in_sizes; (void)n_in; (void)out_size; (void)ws_size;
  const float* user = (const float*)d_in[0];
  const float* item = (const float*)d_in[1];
  const int* adj_rows = (const int*)d_in[2];
  const int* adj_cols = (const int*)d_in[3];
  const float* adj_vals = (const float*)d_in[4];
  const float* wq = (const float*)d_in[5];
  const float* bq = (const float*)d_in[6];
  const float* wk = (const float*)d_in[7];
  const float* wv = (const float*)d_in[9];
  const float* bv = (const float*)d_in[10];
  const float* fw = (const float*)d_in[11];
  const float* fb = (const float*)d_in[12];

  float* out = (float*)d_out;
  float* allemb = out;                    // [N,D]
  float* atten = out + (size_t)N_ * D_;   // [N,D]
  float* fusion = out + (size_t)2 * N_ * D_;

  char* ws = (char*)d_ws;
  size_t off = 0;
  auto alloc = [&](size_t bytes) { char* p = ws + off; off += (bytes + 255) & ~(size_t)255; return p; };
  float* ego_a = (float*)alloc((size_t)N_ * D_ * 4);
  float* ego_b = (float*)alloc((size_t)N_ * D_ * 4);
  float* qkbuf = (float*)alloc((size_t)N_ * D_ * 4);
  u16* Gh = (u16*)alloc((size_t)N_ * D_ * 2);
  u16* Gl = (u16*)alloc((size_t)N_ * D_ * 2);
  u16* XTh = (u16*)alloc((size_t)N_ * D_ * 2);
  u16* XTl = (u16*)alloc((size_t)N_ * D_ * 2);
  int2* gbuf = (int2*)alloc((size_t)N_ * CAP_ * 8);  // (col,val) pairs (aliased by z1)
  float* z1 = (float*)gbuf;                          // lifetimes disjoint
  float* z2 = (float*)alloc((size_t)N_ * D_ * 4);
  int* topk_idx = (int*)alloc((size_t)N_ * 32 * 4);
  int* ccol = (int*)alloc((size_t)E_ * 4);
  float* cval = (float*)alloc((size_t)E_ * 4);
  int* cnt = (int*)alloc((size_t)N_ * 4);
  int* row_ptr = (int*)alloc((size_t)(N_ + 1) * 4);
  int* cursor = (int*)alloc((size_t)N_ * 4);
  float* M = (float*)alloc(128 * 128 * 4);
  float* bqk = (float*)alloc(128 * 4);
  float* wvT = (float*)alloc(128 * 128 * 4);
  float* fwdT = (float*)alloc(128 * 128 * 4);
  float* cs1 = (float*)alloc(16 * 128 * 4);           // 16 replicas
  float* cs2 = (float*)alloc(16 * 128 * 4);
  float* C2 = (float*)alloc(128 * 128 * 4);
  float* C2part = (float*)alloc((size_t)256 * 16384 * 4);   // 16 MB partials
  float* svec = (float*)alloc(128 * 4);
  float* tau = (float*)alloc((size_t)N_ * 4);
  int* gcount = (int*)alloc((size_t)N_ * 4);          // legacy (unused by hot path)
  int* gstripcnt = (int*)alloc((size_t)N_ * 16 * 4);  // per (row,strip) counts
  int* failq = (int*)alloc(64 * 4);
  int* failn = (int*)alloc(4);
  double* fsim = (double*)alloc((size_t)64 * N_ * 8);

  k_init<<<64, 256, 0, stream>>>(wq, wk, bq, wv, fw, M, bqk, wvT, fwdT, cnt, cs1, cs2, svec, gcount, failn);
  k_concat<<<8192, 256, 0, stream>>>(user, item, ego_a);
  k_hist<<<2048, 256, 0, stream>>>(adj_rows, cnt);
  k_scan<<<1, 1024, 0, stream>>>(cnt, row_ptr, cursor);
  k_scatter<<<2048, 256, 0, stream>>>(adj_rows, adj_cols, adj_vals, cursor, ccol, cval);

  k_spmm<<<N_, 128, 0, stream>>>(ego_a, ego_b, allemb, row_ptr, ccol, cval, 1, 0);
  k_spmm<<<N_, 128, 0, stream>>>(ego_b, ego_a, allemb, row_ptr, ccol, cval, 0, 0);
  k_spmm<<<N_, 128, 0, stream>>>(ego_a, ego_b, allemb, row_ptr, ccol, cval, 0, 1);
  // ego3 = ego_b; allemb = mean of layers (div folded into last pass)

  k_split_t<<<256, 256, 0, stream>>>(ego_b, Gh, Gl, XTh, XTl, svec);
  k_c2mfma<<<256, 256, 0, stream>>>(XTh, XTl, C2part);
  k_c2red<<<64, 256, 0, stream>>>(C2part, C2);
  k_tau<<<2048, 128, 0, stream>>>(ego_b, C2, svec, tau);   // thin-tile v2

  k_qk<<<2048, 256, 0, stream>>>(ego_b, M, bqk, qkbuf);
  k_simmfma<<<2048, 256, 0, stream>>>(Gh, Gl, tau, gstripcnt, gbuf);
  k_check<<<64, 256, 0, stream>>>(gstripcnt, failq, failn);
  k_refine<<<4096, 256, 0, stream>>>(gstripcnt, gbuf, topk_idx);
  k_fallback<<<64, 256, 0, stream>>>(ego_b, failq, failn, fsim, topk_idx);
  k_attn<<<N_, 128, 0, stream>>>(ego_b, qkbuf, topk_idx);          // -> sa in qkbuf
  k_attnmm<<<2048, 256, 0, stream>>>(qkbuf, ego_b, wvT, bv, atten);

  k_fuse1<<<2048, 256, 0, stream>>>(allemb, atten, fwdT, fb, z1, z2, cs1, cs2);
  k_fuse2<<<8192, 256, 0, stream>>>(allemb, atten, z1, z2, cs1, cs2, fusion);
}

// Round 10
// 664.782 us; speedup vs baseline: 2.1812x; 1.0336x over previous
//
#include <hip/hip_runtime.h>
#include <math.h>

#define U_ 8192
#define I_ 8192
#define D_ 128
#define E_ 524288
#define N_ 16384
#define K_ 32
#define CAP_ 512

typedef unsigned short u16;
typedef unsigned int u32;
typedef unsigned long long u64;
typedef __attribute__((ext_vector_type(8))) short bf16x8;
typedef __attribute__((ext_vector_type(4))) float f32x4;

// ---------------------------------------------------------------- init ------
__global__ void k_init(const float* __restrict__ wq, const float* __restrict__ wk,
                       const float* __restrict__ bq, const float* __restrict__ wv,
                       const float* __restrict__ fw,
                       float* __restrict__ M, float* __restrict__ bqk,
                       float* __restrict__ wvT, float* __restrict__ fwdT,
                       int* __restrict__ cnt, float* __restrict__ cs1,
                       float* __restrict__ cs2,
                       float* __restrict__ svec, int* __restrict__ gcount,
                       int* __restrict__ failn) {
  const int tid = blockIdx.x * 256 + threadIdx.x;   // 64 blocks -> 16384 threads
  cnt[tid] = 0;
  gcount[tid] = 0;
  if (tid < 2048) { cs1[tid] = 0.f; cs2[tid] = 0.f; }   // 16 replicas x 128
  if (tid < 128) svec[tid] = 0.f;
  if (tid == 0) *failn = 0;
  // M[i][j] = sum_l wq[l,i]*wk[l,j]  (wq^T wk)
  const int i = tid >> 7, j = tid & 127;
  float s = 0.f;
  for (int l = 0; l < 128; ++l) s += wq[l * 128 + i] * wk[l * 128 + j];
  M[tid] = s;
  wvT[i * 128 + j] = wv[j * 128 + i];
  fwdT[i * 128 + j] = fw[j * 128 + i];   // fwdT[d][j] = fw[j][d] (d-major)
  if (tid < 128) {
    float s2 = 0.f;
    for (int l = 0; l < 128; ++l) s2 += bq[l] * wk[l * 128 + tid];
    bqk[tid] = s2;
  }
}

// concat + edge histogram merged (same 2M-thread grid; E_ = 0.5M guarded)
__global__ void k_concat(const float* __restrict__ user, const float* __restrict__ item,
                         float* __restrict__ ego,
                         const int* __restrict__ rows, int* __restrict__ cnt) {
  const int i = blockIdx.x * 256 + threadIdx.x;     // 8192 blocks, exact N*D
  ego[i] = (i < U_ * D_) ? user[i] : item[i - U_ * D_];
  if (i < E_) atomicAdd(&cnt[rows[i]], 1);
}

// wave-scan: shfl_up intra-wave + 16-partial scan; 4 barriers/chunk.
__global__ void k_scan(const int* __restrict__ cnt, int* __restrict__ row_ptr,
                       int* __restrict__ cursor) {
  __shared__ int wsum[16];
  __shared__ int carry_s;
  const int t = threadIdx.x;                 // 1024 threads
  const int lane = t & 63, wid = t >> 6;
  if (t == 0) carry_s = 0;
  __syncthreads();
  for (int c = 0; c < N_ / 1024; ++c) {
    const int x = cnt[c * 1024 + t];
    int incl = x;
#pragma unroll
    for (int off = 1; off < 64; off <<= 1) {
      const int v = __shfl_up(incl, off, 64);
      if (lane >= off) incl += v;
    }
    if (lane == 63) wsum[wid] = incl;
    __syncthreads();
    if (wid == 0) {
      int s = (lane < 16) ? wsum[lane] : 0;
#pragma unroll
      for (int off = 1; off < 16; off <<= 1) {
        const int v = __shfl_up(s, off, 64);
        if (lane >= off) s += v;
      }
      if (lane < 16) wsum[lane] = s;
    }
    __syncthreads();
    const int carry = carry_s;
    const int wbase = wid ? wsum[wid - 1] : 0;
    const int excl = carry + wbase + incl - x;
    row_ptr[c * 1024 + t] = excl;
    cursor[c * 1024 + t] = excl;
    __syncthreads();
    if (t == 1023) carry_s += wsum[15];
    __syncthreads();
  }
  if (t == 0) row_ptr[N_] = carry_s;
}

__global__ void k_scatter(const int* __restrict__ rows, const int* __restrict__ cols,
                          const float* __restrict__ vals, int* __restrict__ cursor,
                          int* __restrict__ ccol, float* __restrict__ cval) {
  const int e = blockIdx.x * 256 + threadIdx.x;
  const int r = rows[e];
  const int p = atomicAdd(&cursor[r], 1);
  ccol[p] = cols[e];
  cval[p] = vals[e];
}

// ---------------------------------------------------------------- SpMM ------
// v3: 8 independent double accumulators (avg degree 32 -> 4 full iters, 8
// gathers in flight); `last` folds the /3.
__global__ __launch_bounds__(128) void k_spmm(const float* __restrict__ x,
                                              float* __restrict__ y,
                                              float* __restrict__ sum,
                                              const int* __restrict__ row_ptr,
                                              const int* __restrict__ ccol,
                                              const float* __restrict__ cval,
                                              const int first, const int last) {
  const int r = blockIdx.x, d = threadIdx.x;
  const int b = row_ptr[r], e = row_ptr[r + 1];
  double a[8];
#pragma unroll
  for (int u = 0; u < 8; ++u) a[u] = 0.0;
  int i = b;
  for (; i + 7 < e; i += 8) {
#pragma unroll
    for (int u = 0; u < 8; ++u)
      a[u] += (double)cval[i + u] * (double)x[ccol[i + u] * 128 + d];
  }
  for (; i < e; ++i)
    a[0] += (double)cval[i] * (double)x[ccol[i] * 128 + d];
  const float f = (float)((((a[0] + a[1]) + (a[2] + a[3])) + ((a[4] + a[5]) + (a[6] + a[7]))));
  y[r * 128 + d] = f;
  float s = first ? f : sum[r * 128 + d] + f;
  if (last) s = s / 3.0f;
  sum[r * 128 + d] = s;
}

// ------------------------------------------------- split + transpose --------
__global__ __launch_bounds__(256) void k_split_t(const float* __restrict__ x,
                                                 u16* __restrict__ Gh, u16* __restrict__ Gl,
                                                 u16* __restrict__ XTh, u16* __restrict__ XTl,
                                                 float* __restrict__ svec) {
  __shared__ u16 lh[128 * 66];
  __shared__ u16 ll[128 * 66];
  const int tid = threadIdx.x;
  const int r0 = blockIdx.x * 64;
  float colsum = 0.f;
  for (int s = 0; s < 32; ++s) {
    const int idx = tid + s * 256;
    const int r = idx >> 7, d = idx & 127;
    const float v = x[(r0 + r) * 128 + d];
    colsum += v;
    unsigned int u = __float_as_uint(v);
    u += 0x7fffu + ((u >> 16) & 1u);
    const u16 h = (u16)(u >> 16);
    const float hf = __uint_as_float(((unsigned int)h) << 16);
    const float l = v - hf;
    unsigned int u2 = __float_as_uint(l);
    u2 += 0x7fffu + ((u2 >> 16) & 1u);
    const u16 lo = (u16)(u2 >> 16);
    Gh[(r0 + r) * 128 + d] = h;
    Gl[(r0 + r) * 128 + d] = lo;
    lh[d * 66 + r] = h;
    ll[d * 66 + r] = lo;
  }
  atomicAdd(&svec[tid & 127], colsum);
  __syncthreads();
  for (int s = 0; s < 32; ++s) {
    const int idx = tid + s * 256;
    const int d = idx >> 6, rr = idx & 63;
    XTh[d * 16384 + r0 + rr] = lh[d * 66 + rr];
    XTl[d * 16384 + r0 + rr] = ll[d * 66 + rr];
  }
}

// ---------------------------------------------------------------- C2 --------
__global__ __launch_bounds__(256) void k_c2mfma(const u16* __restrict__ XTh,
                                                const u16* __restrict__ XTl,
                                                float* __restrict__ C2part) {
  const int tid = threadIdx.x, w = tid >> 6, lane = tid & 63;
  const int n16 = lane & 15, kq = lane >> 4;
  const int c0 = blockIdx.x * 64;
  f32x4 acc[2][8];
#pragma unroll
  for (int a = 0; a < 2; ++a)
#pragma unroll
    for (int b = 0; b < 8; ++b) acc[a][b] = (f32x4){0.f, 0.f, 0.f, 0.f};
  for (int ks = 0; ks < 2; ++ks) {
    const int c = c0 + ks * 32 + kq * 8;
    bf16x8 Fh[8], Fl[8];
#pragma unroll
    for (int g = 0; g < 8; ++g) {
      const int base = (g * 16 + n16) * 16384 + c;
      Fh[g] = *(const bf16x8*)&XTh[base];
      Fl[g] = *(const bf16x8*)&XTl[base];
    }
#pragma unroll
    for (int a = 0; a < 2; ++a) {
      const int tr = w * 2 + a;
#pragma unroll
      for (int b = 0; b < 8; ++b) {
        acc[a][b] = __builtin_amdgcn_mfma_f32_16x16x32_bf16(Fl[tr], Fh[b], acc[a][b], 0, 0, 0);
        acc[a][b] = __builtin_amdgcn_mfma_f32_16x16x32_bf16(Fh[tr], Fl[b], acc[a][b], 0, 0, 0);
        acc[a][b] = __builtin_amdgcn_mfma_f32_16x16x32_bf16(Fh[tr], Fh[b], acc[a][b], 0, 0, 0);
      }
    }
  }
  float* dst = C2part + (size_t)blockIdx.x * 16384;
#pragma unroll
  for (int a = 0; a < 2; ++a) {
    const int tr = w * 2 + a;
#pragma unroll
    for (int b = 0; b < 8; ++b)
#pragma unroll
      for (int i = 0; i < 4; ++i)
        dst[(tr * 16 + kq * 4 + i) * 128 + b * 16 + n16] = acc[a][b][i];
  }
}

__global__ void k_c2red(const float* __restrict__ C2part, float* __restrict__ C2) {
  const int e = blockIdx.x * 256 + threadIdx.x;   // 64 blocks -> 16384
  float s = 0.f;
  for (int b = 0; b < 256; ++b) s += C2part[(size_t)b * 16384 + e];
  C2[e] = s;
}

// ---------------------------------------------------------------- tau -------
// v3: shuffle-based double reduction -- both sums (x.y and x.svec) reduced
// in one interleaved shfl_xor tree per row; ONE barrier per block (was 112
// barrier-stepped LDS reductions).  Tree order changes tau by ~1e-16 rel;
// harmless: containment is structural (count>=36 => top-32 above tau).
__global__ __launch_bounds__(128) void k_tau(const float* __restrict__ x,
                                             const float* __restrict__ C2,
                                             const float* __restrict__ svec,
                                             float* __restrict__ tau) {
  __shared__ float xs[8][128];
  __shared__ double r1[8][2], r2[8][2];
  const int tid = threadIdx.x;
  const int lane = tid & 63, wid = tid >> 6;
  const int n0 = blockIdx.x * 8;
#pragma unroll
  for (int rr = 0; rr < 8; ++rr) xs[rr][tid] = x[(n0 + rr) * 128 + tid];
  __syncthreads();
  double y[8];
#pragma unroll
  for (int rr = 0; rr < 8; ++rr) y[rr] = 0.0;
  for (int k2 = 0; k2 < 128; ++k2) {
    const double c = (double)C2[k2 * 128 + tid];
#pragma unroll
    for (int rr = 0; rr < 8; ++rr) y[rr] += (double)xs[rr][k2] * c;
  }
  const double sv = (double)svec[tid];
#pragma unroll
  for (int rr = 0; rr < 8; ++rr) {
    double v1 = (double)xs[rr][tid] * y[rr];
    double v2 = (double)xs[rr][tid] * sv;
#pragma unroll
    for (int off = 32; off; off >>= 1) {
      v1 += __shfl_xor(v1, off, 64);
      v2 += __shfl_xor(v2, off, 64);
    }
    if (lane == 0) { r1[rr][wid] = v1; r2[rr][wid] = v2; }
  }
  __syncthreads();
  if (tid < 8) {
    const double exy = (r1[tid][0] + r1[tid][1]) / 16384.0;
    const double m = (r2[tid][0] + r2[tid][1]) / 16384.0;
    double var = exy - m * m;
    if (var < 0.0) var = 0.0;
    tau[n0 + tid] = (float)(m + 2.55 * sqrt(var));
  }
}

// ---------------------------------------------------------------- qk --------
__global__ __launch_bounds__(256) void k_qk(const float* __restrict__ ego,
                                            const float* __restrict__ M,
                                            const float* __restrict__ bqk,
                                            float* __restrict__ qkout) {
  __shared__ float xs[8][128];
  const int tid = threadIdx.x;
  const int r0 = blockIdx.x * 8;
#pragma unroll
  for (int s = 0; s < 4; ++s) {
    const int idx = tid + s * 256;
    xs[idx >> 7][idx & 127] = ego[r0 * 128 + idx];
  }
  __syncthreads();
  const int j = tid & 127, h = tid >> 7;
  const float bj = bqk[j];
  float acc[4];
#pragma unroll
  for (int r = 0; r < 4; ++r) acc[r] = bj;
  for (int d = 0; d < 128; d += 4) {
    const float w0 = M[(d + 0) * 128 + j];
    const float w1 = M[(d + 1) * 128 + j];
    const float w2 = M[(d + 2) * 128 + j];
    const float w3 = M[(d + 3) * 128 + j];
#pragma unroll
    for (int r = 0; r < 4; ++r) {
      const float4 xv = *(const float4*)&xs[h * 4 + r][d];
      acc[r] += xv.x * w0 + xv.y * w1 + xv.z * w2 + xv.w * w3;
    }
  }
#pragma unroll
  for (int r = 0; r < 4; ++r)
    qkout[(r0 + h * 4 + r) * 128 + j] = acc[r];
}

// ------------------------------------------------------- sim via MFMA -------
// Round-8 winner, untouched (protected): round-6 cfg + swizzled gload_lds.
__device__ __forceinline__ void gload_lds16(const u16* g, u16* l) {
  __builtin_amdgcn_global_load_lds(
      (const __attribute__((address_space(1))) void*)g,
      (__attribute__((address_space(3))) void*)l, 16, 0, 0);
}

__global__ __launch_bounds__(256) void k_simmfma(const u16* __restrict__ Gh,
                                                 const u16* __restrict__ Gl,
                                                 const float* __restrict__ tau,
                                                 int* __restrict__ gstripcnt,
                                                 int2* __restrict__ gbuf) {
  __shared__ __align__(16) u16 lh[64 * 128];   // 16 KB, linear 256-B rows
  __shared__ int cnt128[128];
  const int tid = threadIdx.x;
  const int w = tid >> 6, lane = tid & 63;
  const int strip = blockIdx.x & 15, rgrp = blockIdx.x >> 4;
  const int n16 = lane & 15, kq = lane >> 4;

  if (tid < 128) cnt128[tid] = 0;

  const int rowbase = rgrp * 128 + w * 32;
  bf16x8 Bh[2][4], Bl[2][4];
#pragma unroll
  for (int rg = 0; rg < 2; ++rg) {
    const int row = rowbase + rg * 16 + n16;
#pragma unroll
    for (int q = 0; q < 4; ++q) {
      Bh[rg][q] = *(const bf16x8*)&Gh[row * 128 + q * 32 + kq * 8];
      Bl[rg][q] = *(const bf16x8*)&Gl[row * 128 + q * 32 + kq * 8];
    }
  }
  const float tau0 = tau[rowbase + n16];
  const float tau1 = tau[rowbase + 16 + n16];
  const int col0 = strip * 1024;

  for (int st = 0; st < 16; ++st) {
    const int cb = col0 + st * 64;
    __syncthreads();
#pragma unroll
    for (int ii = 0; ii < 4; ++ii) {
      const int srow = w * 16 + ii * 4 + kq;
      const int chunk = n16 ^ (srow & 7);
      gload_lds16(Gh + (((size_t)(cb + srow)) << 7) + chunk * 8,
                  lh + ((w * 16 + ii * 4) << 7));
    }
    __syncthreads();   // drains vmcnt: staged tile visible to all waves
#pragma unroll
    for (int ct = 0; ct < 4; ++ct) {
      const int ar = ct * 16 + n16;
      const char* lbase = (const char*)lh + ar * 256;
      bf16x8 Ah[4];
#pragma unroll
      for (int q = 0; q < 4; ++q)
        Ah[q] = *(const bf16x8*)(lbase + ((q * 64 + kq * 16) ^ ((ar & 7) << 4)));
#pragma unroll
      for (int rg = 0; rg < 2; ++rg) {
        f32x4 p = {0.f, 0.f, 0.f, 0.f};
        f32x4 r = {0.f, 0.f, 0.f, 0.f};
#pragma unroll
        for (int q = 0; q < 4; ++q) {
          p = __builtin_amdgcn_mfma_f32_16x16x32_bf16(Ah[q], Bh[rg][q], p, 0, 0, 0);
          r = __builtin_amdgcn_mfma_f32_16x16x32_bf16(Ah[q], Bl[rg][q], r, 0, 0, 0);
        }
        const float tv = rg ? tau1 : tau0;
        const int lrow = w * 32 + rg * 16 + n16;     // block-local row 0..127
        const int row = rgrp * 128 + lrow;
#pragma unroll
        for (int i = 0; i < 4; ++i) {
          const float v = p[i] + r[i];
          if (v > tv) {
            const int c = cb + ct * 16 + kq * 4 + i;
            const int pos = atomicAdd(&cnt128[lrow], 1);   // LDS atomic
            if (pos < 32)
              gbuf[row * CAP_ + strip * 32 + pos] = make_int2(c, __float_as_int(v));
          }
        }
      }
    }
  }
  __syncthreads();
  if (tid < 128) gstripcnt[(rgrp * 128 + tid) * 16 + strip] = cnt128[tid];
}

// Top-32 by stored fp32 sim values via RANK-SCATTER on packed u64 keys.
// Now also performs the count check (k_check merged): bad rows are pushed
// to failq by lane 0 of the owning wave.
__global__ __launch_bounds__(256) void k_refine(const int* __restrict__ gstripcnt,
                                                const int2* __restrict__ gbuf,
                                                int* __restrict__ topk_idx,
                                                int* __restrict__ failq,
                                                int* __restrict__ failn) {
  __shared__ u64 lk[4][CAP_];
  const int tid = threadIdx.x, w = tid >> 6, lane = tid & 63;
  const int n = blockIdx.x * 4 + w;

  const int scn = (lane < 16) ? gstripcnt[n * 16 + lane] : 0;
  int total = 0, over = 0;
#pragma unroll
  for (int s = 0; s < 16; ++s) {
    const int c = __shfl(scn, s, 64);
    total += c;
    over |= (c > 32);
  }
  const int bad = (total < 36 || total > CAP_ || over);
  const int cnt = bad ? 0 : total;

  // compact the 16 segments into lk[w][0..cnt)
  int base = 0;
#pragma unroll
  for (int s = 0; s < 16; ++s) {
    const int c = __shfl(scn, s, 64);
    if (!bad && lane < c) {
      const int2 p = gbuf[n * CAP_ + s * 32 + lane];
      u32 uv = (u32)p.y;
      uv = (uv >> 31) ? ~uv : (uv | 0x80000000u);
      lk[w][base + lane] = ((u64)uv << 32) | (u64)(16383 - p.x);
    }
    base += bad ? 0 : c;
  }
  __syncthreads();

  for (int ci = lane; ci < cnt; ci += 64) {
    const u64 kk = lk[w][ci];
    int r = 0;
#pragma unroll 4
    for (int j = 0; j < cnt; ++j)
      r += (lk[w][j] > kk) ? 1 : 0;
    if (r < 32) topk_idx[n * 32 + r] = 16383 - (int)(u32)(kk & 0xffffffffu);
  }
  if (bad) {
    if (lane == 0) {
      const int s = atomicAdd(failn, 1);
      if (s < 64) failq[s] = n;
    }
    if (lane < 32) topk_idx[n * 32 + lane] = 0;  // placeholder; fallback overwrites
  }
}

// exact fp64 full-row top-32 for statistically-failed rows (expected: none)
__global__ __launch_bounds__(256) void k_fallback(const float* __restrict__ x,
                                                  const int* __restrict__ failq,
                                                  const int* __restrict__ failn,
                                                  double* __restrict__ fsim,
                                                  int* __restrict__ topk_idx) {
  const int nf = *failn;
  const int which = blockIdx.x;
  if (which >= nf || which >= 64) return;
  const int row = failq[which];
  __shared__ float xs[128];
  __shared__ double bm[256];
  __shared__ int bc[256];
  const int tid = threadIdx.x;
  if (tid < 128) xs[tid] = x[row * 128 + tid];
  __syncthreads();
  double* fs = fsim + (size_t)which * 16384;
  for (int c = tid; c < 16384; c += 256) {
    const float4* xp = (const float4*)&x[c * 128];
    double a = 0.0;
    for (int d = 0; d < 32; ++d) {
      const float4 v = xp[d];
      a += (double)xs[d * 4 + 0] * (double)v.x + (double)xs[d * 4 + 1] * (double)v.y +
           (double)xs[d * 4 + 2] * (double)v.z + (double)xs[d * 4 + 3] * (double)v.w;
    }
    fs[c] = a;
  }
  __syncthreads();
  for (int r = 0; r < 32; ++r) {
    double m = -1.0e300; int mc = 0;
    for (int c = tid; c < 16384; c += 256) {
      const double v = fs[c];
      if (v > m || (v == m && c < mc)) { m = v; mc = c; }
    }
    bm[tid] = m; bc[tid] = mc;
    __syncthreads();
    for (int s = 128; s; s >>= 1) {
      if (tid < s) {
        if (bm[tid + s] > bm[tid] || (bm[tid + s] == bm[tid] && bc[tid + s] < bc[tid])) {
          bm[tid] = bm[tid + s]; bc[tid] = bc[tid + s];
        }
      }
      __syncthreads();
    }
    if (tid == 0) { topk_idx[row * 32 + r] = bc[0]; fs[bc[0]] = -1.0e300; }
    __syncthreads();
  }
}

// ------------------------------------------------------- attention ----------
// ends at sa (weighted sample sum), written in place into qkbuf.
__global__ __launch_bounds__(128) void k_attn(const float* __restrict__ ego,
                                              float* __restrict__ qk,
                                              const int* __restrict__ topk_idx) {
  __shared__ float qv[128];
  __shared__ float sm[32 * 129];
  __shared__ int tki[32];
  __shared__ float sc[32];
  __shared__ float psum[128];
  const int n = blockIdx.x, tid = threadIdx.x;
  qv[tid] = qk[n * 128 + tid];
  if (tid < 32) tki[tid] = topk_idx[n * 32 + tid] & 16383;
  __syncthreads();
  for (int e = tid; e < 32 * 128; e += 128) {
    const int k2 = e >> 7, d = e & 127;
    sm[k2 * 129 + d] = ego[tki[k2] * 128 + d];
  }
  __syncthreads();
  {
    const int kk = tid & 31, part = tid >> 5;
    float s = 0.f;
    const int d0 = part * 32;
    for (int d = d0; d < d0 + 32; ++d) s += qv[d] * sm[kk * 129 + d];
    psum[tid] = s;
  }
  __syncthreads();
  if (tid < 32) {
    float v = psum[tid] + psum[tid + 32] + psum[tid + 64] + psum[tid + 96];
    v *= (1.0f / 11.313708498984760f);    // 1/sqrt(128)
    float m = v;
#pragma unroll
    for (int off = 16; off; off >>= 1) m = fmaxf(m, __shfl_xor(m, off, 32));
    const float e = expf(v - m);
    float ssum = e;
#pragma unroll
    for (int off = 16; off; off >>= 1) ssum += __shfl_xor(ssum, off, 32);
    sc[tid] = e / ssum;
  }
  __syncthreads();
  float sad = 0.f;
  for (int k2 = 0; k2 < 32; ++k2) sad += sc[k2] * sm[k2 * 129 + tid];
  qk[n * 128 + tid] = sad;            // sa, in place (qv fully consumed)
}

// ------------------------------------------- attnmm + fuse1 fused -----------
// Phase 1: atten = sa@wvT + bv + 0.1*ego (thin-tile, 8 rows/block); atten
// rows stay in LDS.  Phase 2: fuse gating (tanh projections + partial
// column-softmax sums) on the same rows -- saves the 8MB atten re-read and
// a launch.  Math order identical to the previous k_attnmm then k_fuse1.
__global__ __launch_bounds__(256) void k_attnfuse(const float* __restrict__ sa,
                                                  const float* __restrict__ ego,
                                                  const float* __restrict__ allemb,
                                                  const float* __restrict__ wvT,
                                                  const float* __restrict__ bv,
                                                  const float* __restrict__ fwdT,
                                                  const float* __restrict__ fb,
                                                  float* __restrict__ atten,
                                                  float* __restrict__ z1,
                                                  float* __restrict__ z2,
                                                  float* __restrict__ cs1,
                                                  float* __restrict__ cs2) {
  __shared__ float xs[8][128];    // sa rows
  __shared__ float xa[8][128];    // allemb rows
  __shared__ float as_[8][128];   // atten rows (computed)
  __shared__ float red1[2][128];
  __shared__ float red2[2][128];
  const int tid = threadIdx.x;
  const int r0 = blockIdx.x * 8;
#pragma unroll
  for (int s = 0; s < 4; ++s) {
    const int idx = tid + s * 256;
    const int rr = idx >> 7, d = idx & 127;
    xs[rr][d] = sa[(r0 + rr) * 128 + d];
    xa[rr][d] = allemb[(r0 + rr) * 128 + d];
  }
  __syncthreads();
  const int j = tid & 127, h = tid >> 7;
  // phase 1: projection
  {
    const float bj = bv[j];
    float acc[4];
#pragma unroll
    for (int r = 0; r < 4; ++r) acc[r] = bj;
    for (int d = 0; d < 128; d += 4) {
      const float w0 = wvT[(d + 0) * 128 + j];
      const float w1 = wvT[(d + 1) * 128 + j];
      const float w2 = wvT[(d + 2) * 128 + j];
      const float w3 = wvT[(d + 3) * 128 + j];
#pragma unroll
      for (int r = 0; r < 4; ++r) {
        const float4 xv = *(const float4*)&xs[h * 4 + r][d];
        acc[r] += xv.x * w0 + xv.y * w1 + xv.z * w2 + xv.w * w3;
      }
    }
#pragma unroll
    for (int r = 0; r < 4; ++r) {
      const int n = r0 + h * 4 + r;
      const float av = acc[r] + 0.1f * ego[n * 128 + j];
      atten[n * 128 + j] = av;
      as_[h * 4 + r][j] = av;
    }
  }
  __syncthreads();
  // phase 2: fuse gating
  const float fbj = fb[j];
  float acc1[4], acc2[4];
#pragma unroll
  for (int r = 0; r < 4; ++r) { acc1[r] = fbj; acc2[r] = fbj; }
  for (int d = 0; d < 128; d += 4) {
    const float w0 = fwdT[(d + 0) * 128 + j];
    const float w1 = fwdT[(d + 1) * 128 + j];
    const float w2 = fwdT[(d + 2) * 128 + j];
    const float w3 = fwdT[(d + 3) * 128 + j];
#pragma unroll
    for (int r = 0; r < 4; ++r) {
      const int rr = h * 4 + r;
      const float4 xv = *(const float4*)&xa[rr][d];
      const float4 av = *(const float4*)&as_[rr][d];
      acc1[r] += xv.x * w0 + xv.y * w1 + xv.z * w2 + xv.w * w3;
      acc2[r] += av.x * w0 + av.y * w1 + av.z * w2 + av.w * w3;
    }
  }
  float ls1 = 0.f, ls2 = 0.f;
#pragma unroll
  for (int r = 0; r < 4; ++r) {
    const int rr = h * 4 + r;
    const float t1 = tanhf(acc1[r]);
    const float t2 = tanhf(acc2[r]);
    z1[(r0 + rr) * 128 + j] = t1;
    z2[(r0 + rr) * 128 + j] = t2;
    ls1 += expf(t1 - 1.0f);
    ls2 += expf(t2 - 1.0f);
  }
  red1[h][j] = ls1;
  red2[h][j] = ls2;
  __syncthreads();
  if (h == 0) {
    const int rep = blockIdx.x & 15;
    atomicAdd(&cs1[rep * 128 + j], red1[0][j] + red1[1][j]);
    atomicAdd(&cs2[rep * 128 + j], red2[0][j] + red2[1][j]);
  }
}

__global__ void k_fuse2(const float* __restrict__ allemb, const float* __restrict__ atten,
                        const float* __restrict__ z1, const float* __restrict__ z2,
                        const float* __restrict__ cs1, const float* __restrict__ cs2,
                        float* __restrict__ fusion) {
  __shared__ float s1[128], s2[128];
  const int tid = threadIdx.x;
  if (tid < 128) {
    float a = 0.f, b = 0.f;
#pragma unroll
    for (int rep = 0; rep < 16; ++rep) {
      a += cs1[rep * 128 + tid];
      b += cs2[rep * 128 + tid];
    }
    s1[tid] = a; s2[tid] = b;
  }
  __syncthreads();
  const int i = blockIdx.x * 256 + tid;
  const int j = i & 127;
  const float a1 = expf(z1[i] - 1.0f) / s1[j];
  const float a2 = expf(z2[i] - 1.0f) / s2[j];
  fusion[i] = a1 * allemb[i] + a2 * atten[i];
}

// ---------------------------------------------------------------- launch ----
extern "C" void kernel_launch(void* const* d_in, const int* in_sizes, int n_in,
                              void* d_out, int out_size, void* d_ws, size_t ws_size,
                              hipStream_t stream) {
  (void)in_sizes; (void)n_in; (void)out_size; (void)ws_size;
  const float* user = (const float*)d_in[0];
  const float* item = (const float*)d_in[1];
  const int* adj_rows = (const int*)d_in[2];
  const int* adj_cols = (const int*)d_in[3];
  const float* adj_vals = (const float*)d_in[4];
  const float* wq = (const float*)d_in[5];
  const float* bq = (const float*)d_in[6];
  const float* wk = (const float*)d_in[7];
  const float* wv = (const float*)d_in[9];
  const float* bv = (const float*)d_in[10];
  const float* fw = (const float*)d_in[11];
  const float* fb = (const float*)d_in[12];

  float* out = (float*)d_out;
  float* allemb = out;                    // [N,D]
  float* atten = out + (size_t)N_ * D_;   // [N,D]
  float* fusion = out + (size_t)2 * N_ * D_;

  char* ws = (char*)d_ws;
  size_t off = 0;
  auto alloc = [&](size_t bytes) { char* p = ws + off; off += (bytes + 255) & ~(size_t)255; return p; };
  float* ego_a = (float*)alloc((size_t)N_ * D_ * 4);
  float* ego_b = (float*)alloc((size_t)N_ * D_ * 4);
  float* qkbuf = (float*)alloc((size_t)N_ * D_ * 4);
  u16* Gh = (u16*)alloc((size_t)N_ * D_ * 2);
  u16* Gl = (u16*)alloc((size_t)N_ * D_ * 2);
  u16* XTh = (u16*)alloc((size_t)N_ * D_ * 2);
  u16* XTl = (u16*)alloc((size_t)N_ * D_ * 2);
  int2* gbuf = (int2*)alloc((size_t)N_ * CAP_ * 8);  // (col,val) pairs (aliased by z1)
  float* z1 = (float*)gbuf;                          // lifetimes disjoint
  float* z2 = (float*)alloc((size_t)N_ * D_ * 4);
  int* topk_idx = (int*)alloc((size_t)N_ * 32 * 4);
  int* ccol = (int*)alloc((size_t)E_ * 4);
  float* cval = (float*)alloc((size_t)E_ * 4);
  int* cnt = (int*)alloc((size_t)N_ * 4);
  int* row_ptr = (int*)alloc((size_t)(N_ + 1) * 4);
  int* cursor = (int*)alloc((size_t)N_ * 4);
  float* M = (float*)alloc(128 * 128 * 4);
  float* bqk = (float*)alloc(128 * 4);
  float* wvT = (float*)alloc(128 * 128 * 4);
  float* fwdT = (float*)alloc(128 * 128 * 4);
  float* cs1 = (float*)alloc(16 * 128 * 4);           // 16 replicas
  float* cs2 = (float*)alloc(16 * 128 * 4);
  float* C2 = (float*)alloc(128 * 128 * 4);
  float* C2part = (float*)alloc((size_t)256 * 16384 * 4);   // 16 MB partials
  float* svec = (float*)alloc(128 * 4);
  float* tau = (float*)alloc((size_t)N_ * 4);
  int* gcount = (int*)alloc((size_t)N_ * 4);          // legacy (unused by hot path)
  int* gstripcnt = (int*)alloc((size_t)N_ * 16 * 4);  // per (row,strip) counts
  int* failq = (int*)alloc(64 * 4);
  int* failn = (int*)alloc(4);
  double* fsim = (double*)alloc((size_t)64 * N_ * 8);

  k_init<<<64, 256, 0, stream>>>(wq, wk, bq, wv, fw, M, bqk, wvT, fwdT, cnt, cs1, cs2, svec, gcount, failn);
  k_concat<<<8192, 256, 0, stream>>>(user, item, ego_a, adj_rows, cnt);   // + hist
  k_scan<<<1, 1024, 0, stream>>>(cnt, row_ptr, cursor);
  k_scatter<<<2048, 256, 0, stream>>>(adj_rows, adj_cols, adj_vals, cursor, ccol, cval);

  k_spmm<<<N_, 128, 0, stream>>>(ego_a, ego_b, allemb, row_ptr, ccol, cval, 1, 0);
  k_spmm<<<N_, 128, 0, stream>>>(ego_b, ego_a, allemb, row_ptr, ccol, cval, 0, 0);
  k_spmm<<<N_, 128, 0, stream>>>(ego_a, ego_b, allemb, row_ptr, ccol, cval, 0, 1);
  // ego3 = ego_b; allemb = mean of layers (div folded into last pass)

  k_split_t<<<256, 256, 0, stream>>>(ego_b, Gh, Gl, XTh, XTl, svec);
  k_c2mfma<<<256, 256, 0, stream>>>(XTh, XTl, C2part);
  k_c2red<<<64, 256, 0, stream>>>(C2part, C2);
  k_tau<<<2048, 128, 0, stream>>>(ego_b, C2, svec, tau);

  k_qk<<<2048, 256, 0, stream>>>(ego_b, M, bqk, qkbuf);
  k_simmfma<<<2048, 256, 0, stream>>>(Gh, Gl, tau, gstripcnt, gbuf);
  k_refine<<<4096, 256, 0, stream>>>(gstripcnt, gbuf, topk_idx, failq, failn);  // + check
  k_fallback<<<64, 256, 0, stream>>>(ego_b, failq, failn, fsim, topk_idx);
  k_attn<<<N_, 128, 0, stream>>>(ego_b, qkbuf, topk_idx);          // -> sa in qkbuf
  k_attnfuse<<<2048, 256, 0, stream>>>(qkbuf, ego_b, allemb, wvT, bv, fwdT, fb,
                                       atten, z1, z2, cs1, cs2);
  k_fuse2<<<8192, 256, 0, stream>>>(allemb, atten, z1, z2, cs1, cs2, fusion);
}

// Round 11
// 662.356 us; speedup vs baseline: 2.1892x; 1.0037x over previous
//
#include <hip/hip_runtime.h>
#include <math.h>

#define U_ 8192
#define I_ 8192
#define D_ 128
#define E_ 524288
#define N_ 16384
#define K_ 32
#define CAP_ 512

typedef unsigned short u16;
typedef unsigned int u32;
typedef unsigned long long u64;
typedef __attribute__((ext_vector_type(8))) short bf16x8;
typedef __attribute__((ext_vector_type(4))) float f32x4;

// ---------------------------------------------------------------- init ------
__global__ void k_init(const float* __restrict__ wq, const float* __restrict__ wk,
                       const float* __restrict__ bq, const float* __restrict__ wv,
                       const float* __restrict__ fw,
                       float* __restrict__ M, float* __restrict__ bqk,
                       float* __restrict__ wvT, float* __restrict__ fwdT,
                       int* __restrict__ cnt, float* __restrict__ cs1,
                       float* __restrict__ cs2,
                       float* __restrict__ svec, int* __restrict__ gcount,
                       int* __restrict__ failn) {
  const int tid = blockIdx.x * 256 + threadIdx.x;   // 64 blocks -> 16384 threads
  cnt[tid] = 0;
  gcount[tid] = 0;
  if (tid < 2048) { cs1[tid] = 0.f; cs2[tid] = 0.f; }   // 16 replicas x 128
  if (tid < 128) svec[tid] = 0.f;
  if (tid == 0) *failn = 0;
  // M[i][j] = sum_l wq[l,i]*wk[l,j]  (wq^T wk)
  const int i = tid >> 7, j = tid & 127;
  float s = 0.f;
  for (int l = 0; l < 128; ++l) s += wq[l * 128 + i] * wk[l * 128 + j];
  M[tid] = s;
  wvT[i * 128 + j] = wv[j * 128 + i];
  fwdT[i * 128 + j] = fw[j * 128 + i];   // fwdT[d][j] = fw[j][d] (d-major)
  if (tid < 128) {
    float s2 = 0.f;
    for (int l = 0; l < 128; ++l) s2 += bq[l] * wk[l * 128 + tid];
    bqk[tid] = s2;
  }
}

// concat (float4) + edge histogram merged: 2048 blocks x 256 = 524288 threads
// = exactly N*D/4 float4 elements = exactly E_ edges (guard-free).
__global__ void k_concat(const float* __restrict__ user, const float* __restrict__ item,
                         float* __restrict__ ego,
                         const int* __restrict__ rows, int* __restrict__ cnt) {
  const int i = blockIdx.x * 256 + threadIdx.x;
  const float4 v = (i < U_ * D_ / 4) ? ((const float4*)user)[i]
                                     : ((const float4*)item)[i - U_ * D_ / 4];
  ((float4*)ego)[i] = v;
  atomicAdd(&cnt[rows[i]], 1);
}

// wave-scan: shfl_up intra-wave + 16-partial scan; 4 barriers/chunk.
__global__ void k_scan(const int* __restrict__ cnt, int* __restrict__ row_ptr,
                       int* __restrict__ cursor) {
  __shared__ int wsum[16];
  __shared__ int carry_s;
  const int t = threadIdx.x;                 // 1024 threads
  const int lane = t & 63, wid = t >> 6;
  if (t == 0) carry_s = 0;
  __syncthreads();
  for (int c = 0; c < N_ / 1024; ++c) {
    const int x = cnt[c * 1024 + t];
    int incl = x;
#pragma unroll
    for (int off = 1; off < 64; off <<= 1) {
      const int v = __shfl_up(incl, off, 64);
      if (lane >= off) incl += v;
    }
    if (lane == 63) wsum[wid] = incl;
    __syncthreads();
    if (wid == 0) {
      int s = (lane < 16) ? wsum[lane] : 0;
#pragma unroll
      for (int off = 1; off < 16; off <<= 1) {
        const int v = __shfl_up(s, off, 64);
        if (lane >= off) s += v;
      }
      if (lane < 16) wsum[lane] = s;
    }
    __syncthreads();
    const int carry = carry_s;
    const int wbase = wid ? wsum[wid - 1] : 0;
    const int excl = carry + wbase + incl - x;
    row_ptr[c * 1024 + t] = excl;
    cursor[c * 1024 + t] = excl;
    __syncthreads();
    if (t == 1023) carry_s += wsum[15];
    __syncthreads();
  }
  if (t == 0) row_ptr[N_] = carry_s;
}

__global__ void k_scatter(const int* __restrict__ rows, const int* __restrict__ cols,
                          const float* __restrict__ vals, int* __restrict__ cursor,
                          int* __restrict__ ccol, float* __restrict__ cval) {
  const int e = blockIdx.x * 256 + threadIdx.x;
  const int r = rows[e];
  const int p = atomicAdd(&cursor[r], 1);
  ccol[p] = cols[e];
  cval[p] = vals[e];
}

// ---------------------------------------------------------------- SpMM ------
// v4: scalar peel to 4-alignment, then int4/float4 index+value loads with 8
// independent double accumulators; `last` folds the /3.
__global__ __launch_bounds__(128) void k_spmm(const float* __restrict__ x,
                                              float* __restrict__ y,
                                              float* __restrict__ sum,
                                              const int* __restrict__ row_ptr,
                                              const int* __restrict__ ccol,
                                              const float* __restrict__ cval,
                                              const int first, const int last) {
  const int r = blockIdx.x, d = threadIdx.x;
  const int b = row_ptr[r], e = row_ptr[r + 1];
  double a[8];
#pragma unroll
  for (int u = 0; u < 8; ++u) a[u] = 0.0;
  int i = b;
  for (; i < e && (i & 3); ++i)
    a[0] += (double)cval[i] * (double)x[ccol[i] * 128 + d];
  for (; i + 7 < e; i += 8) {
    const int4 ca = *(const int4*)&ccol[i];
    const int4 cb = *(const int4*)&ccol[i + 4];
    const float4 va = *(const float4*)&cval[i];
    const float4 vb = *(const float4*)&cval[i + 4];
    a[0] += (double)va.x * (double)x[ca.x * 128 + d];
    a[1] += (double)va.y * (double)x[ca.y * 128 + d];
    a[2] += (double)va.z * (double)x[ca.z * 128 + d];
    a[3] += (double)va.w * (double)x[ca.w * 128 + d];
    a[4] += (double)vb.x * (double)x[cb.x * 128 + d];
    a[5] += (double)vb.y * (double)x[cb.y * 128 + d];
    a[6] += (double)vb.z * (double)x[cb.z * 128 + d];
    a[7] += (double)vb.w * (double)x[cb.w * 128 + d];
  }
  for (; i < e; ++i)
    a[0] += (double)cval[i] * (double)x[ccol[i] * 128 + d];
  const float f = (float)((((a[0] + a[1]) + (a[2] + a[3])) + ((a[4] + a[5]) + (a[6] + a[7]))));
  y[r * 128 + d] = f;
  float s = first ? f : sum[r * 128 + d] + f;
  if (last) s = s / 3.0f;
  sum[r * 128 + d] = s;
}

// ------------------------------------------------- split + transpose --------
__global__ __launch_bounds__(256) void k_split_t(const float* __restrict__ x,
                                                 u16* __restrict__ Gh, u16* __restrict__ Gl,
                                                 u16* __restrict__ XTh, u16* __restrict__ XTl,
                                                 float* __restrict__ svec) {
  __shared__ u16 lh[128 * 66];
  __shared__ u16 ll[128 * 66];
  const int tid = threadIdx.x;
  const int r0 = blockIdx.x * 64;
  float colsum = 0.f;
  for (int s = 0; s < 32; ++s) {
    const int idx = tid + s * 256;
    const int r = idx >> 7, d = idx & 127;
    const float v = x[(r0 + r) * 128 + d];
    colsum += v;
    unsigned int u = __float_as_uint(v);
    u += 0x7fffu + ((u >> 16) & 1u);
    const u16 h = (u16)(u >> 16);
    const float hf = __uint_as_float(((unsigned int)h) << 16);
    const float l = v - hf;
    unsigned int u2 = __float_as_uint(l);
    u2 += 0x7fffu + ((u2 >> 16) & 1u);
    const u16 lo = (u16)(u2 >> 16);
    Gh[(r0 + r) * 128 + d] = h;
    Gl[(r0 + r) * 128 + d] = lo;
    lh[d * 66 + r] = h;
    ll[d * 66 + r] = lo;
  }
  atomicAdd(&svec[tid & 127], colsum);
  __syncthreads();
  for (int s = 0; s < 32; ++s) {
    const int idx = tid + s * 256;
    const int d = idx >> 6, rr = idx & 63;
    XTh[d * 16384 + r0 + rr] = lh[d * 66 + rr];
    XTl[d * 16384 + r0 + rr] = ll[d * 66 + rr];
  }
}

// ---------------------------------------------------------------- C2 --------
__global__ __launch_bounds__(256) void k_c2mfma(const u16* __restrict__ XTh,
                                                const u16* __restrict__ XTl,
                                                float* __restrict__ C2part) {
  const int tid = threadIdx.x, w = tid >> 6, lane = tid & 63;
  const int n16 = lane & 15, kq = lane >> 4;
  const int c0 = blockIdx.x * 64;
  f32x4 acc[2][8];
#pragma unroll
  for (int a = 0; a < 2; ++a)
#pragma unroll
    for (int b = 0; b < 8; ++b) acc[a][b] = (f32x4){0.f, 0.f, 0.f, 0.f};
  for (int ks = 0; ks < 2; ++ks) {
    const int c = c0 + ks * 32 + kq * 8;
    bf16x8 Fh[8], Fl[8];
#pragma unroll
    for (int g = 0; g < 8; ++g) {
      const int base = (g * 16 + n16) * 16384 + c;
      Fh[g] = *(const bf16x8*)&XTh[base];
      Fl[g] = *(const bf16x8*)&XTl[base];
    }
#pragma unroll
    for (int a = 0; a < 2; ++a) {
      const int tr = w * 2 + a;
#pragma unroll
      for (int b = 0; b < 8; ++b) {
        acc[a][b] = __builtin_amdgcn_mfma_f32_16x16x32_bf16(Fl[tr], Fh[b], acc[a][b], 0, 0, 0);
        acc[a][b] = __builtin_amdgcn_mfma_f32_16x16x32_bf16(Fh[tr], Fl[b], acc[a][b], 0, 0, 0);
        acc[a][b] = __builtin_amdgcn_mfma_f32_16x16x32_bf16(Fh[tr], Fh[b], acc[a][b], 0, 0, 0);
      }
    }
  }
  float* dst = C2part + (size_t)blockIdx.x * 16384;
#pragma unroll
  for (int a = 0; a < 2; ++a) {
    const int tr = w * 2 + a;
#pragma unroll
    for (int b = 0; b < 8; ++b)
#pragma unroll
      for (int i = 0; i < 4; ++i)
        dst[(tr * 16 + kq * 4 + i) * 128 + b * 16 + n16] = acc[a][b][i];
  }
}

__global__ void k_c2red(const float* __restrict__ C2part, float* __restrict__ C2) {
  const int e = blockIdx.x * 256 + threadIdx.x;   // 64 blocks -> 16384
  float s = 0.f;
  for (int b = 0; b < 256; ++b) s += C2part[(size_t)b * 16384 + e];
  C2[e] = s;
}

// ---------------------------------------------------------------- tau -------
__global__ __launch_bounds__(128) void k_tau(const float* __restrict__ x,
                                             const float* __restrict__ C2,
                                             const float* __restrict__ svec,
                                             float* __restrict__ tau) {
  __shared__ float xs[8][128];
  __shared__ double r1[8][2], r2[8][2];
  const int tid = threadIdx.x;
  const int lane = tid & 63, wid = tid >> 6;
  const int n0 = blockIdx.x * 8;
#pragma unroll
  for (int rr = 0; rr < 8; ++rr) xs[rr][tid] = x[(n0 + rr) * 128 + tid];
  __syncthreads();
  double y[8];
#pragma unroll
  for (int rr = 0; rr < 8; ++rr) y[rr] = 0.0;
  for (int k2 = 0; k2 < 128; ++k2) {
    const double c = (double)C2[k2 * 128 + tid];
#pragma unroll
    for (int rr = 0; rr < 8; ++rr) y[rr] += (double)xs[rr][k2] * c;
  }
  const double sv = (double)svec[tid];
#pragma unroll
  for (int rr = 0; rr < 8; ++rr) {
    double v1 = (double)xs[rr][tid] * y[rr];
    double v2 = (double)xs[rr][tid] * sv;
#pragma unroll
    for (int off = 32; off; off >>= 1) {
      v1 += __shfl_xor(v1, off, 64);
      v2 += __shfl_xor(v2, off, 64);
    }
    if (lane == 0) { r1[rr][wid] = v1; r2[rr][wid] = v2; }
  }
  __syncthreads();
  if (tid < 8) {
    const double exy = (r1[tid][0] + r1[tid][1]) / 16384.0;
    const double m = (r2[tid][0] + r2[tid][1]) / 16384.0;
    double var = exy - m * m;
    if (var < 0.0) var = 0.0;
    tau[n0 + tid] = (float)(m + 2.55 * sqrt(var));
  }
}

// ---------------------------------------------------------------- qk --------
__global__ __launch_bounds__(256) void k_qk(const float* __restrict__ ego,
                                            const float* __restrict__ M,
                                            const float* __restrict__ bqk,
                                            float* __restrict__ qkout) {
  __shared__ float xs[8][128];
  const int tid = threadIdx.x;
  const int r0 = blockIdx.x * 8;
#pragma unroll
  for (int s = 0; s < 4; ++s) {
    const int idx = tid + s * 256;
    xs[idx >> 7][idx & 127] = ego[r0 * 128 + idx];
  }
  __syncthreads();
  const int j = tid & 127, h = tid >> 7;
  const float bj = bqk[j];
  float acc[4];
#pragma unroll
  for (int r = 0; r < 4; ++r) acc[r] = bj;
  for (int d = 0; d < 128; d += 4) {
    const float w0 = M[(d + 0) * 128 + j];
    const float w1 = M[(d + 1) * 128 + j];
    const float w2 = M[(d + 2) * 128 + j];
    const float w3 = M[(d + 3) * 128 + j];
#pragma unroll
    for (int r = 0; r < 4; ++r) {
      const float4 xv = *(const float4*)&xs[h * 4 + r][d];
      acc[r] += xv.x * w0 + xv.y * w1 + xv.z * w2 + xv.w * w3;
    }
  }
#pragma unroll
  for (int r = 0; r < 4; ++r)
    qkout[(r0 + h * 4 + r) * 128 + j] = acc[r];
}

// ------------------------------------------------------- sim via MFMA -------
// Round-8 winner, untouched (protected): round-6 cfg + swizzled gload_lds.
__device__ __forceinline__ void gload_lds16(const u16* g, u16* l) {
  __builtin_amdgcn_global_load_lds(
      (const __attribute__((address_space(1))) void*)g,
      (__attribute__((address_space(3))) void*)l, 16, 0, 0);
}

__global__ __launch_bounds__(256) void k_simmfma(const u16* __restrict__ Gh,
                                                 const u16* __restrict__ Gl,
                                                 const float* __restrict__ tau,
                                                 int* __restrict__ gstripcnt,
                                                 int2* __restrict__ gbuf) {
  __shared__ __align__(16) u16 lh[64 * 128];   // 16 KB, linear 256-B rows
  __shared__ int cnt128[128];
  const int tid = threadIdx.x;
  const int w = tid >> 6, lane = tid & 63;
  const int strip = blockIdx.x & 15, rgrp = blockIdx.x >> 4;
  const int n16 = lane & 15, kq = lane >> 4;

  if (tid < 128) cnt128[tid] = 0;

  const int rowbase = rgrp * 128 + w * 32;
  bf16x8 Bh[2][4], Bl[2][4];
#pragma unroll
  for (int rg = 0; rg < 2; ++rg) {
    const int row = rowbase + rg * 16 + n16;
#pragma unroll
    for (int q = 0; q < 4; ++q) {
      Bh[rg][q] = *(const bf16x8*)&Gh[row * 128 + q * 32 + kq * 8];
      Bl[rg][q] = *(const bf16x8*)&Gl[row * 128 + q * 32 + kq * 8];
    }
  }
  const float tau0 = tau[rowbase + n16];
  const float tau1 = tau[rowbase + 16 + n16];
  const int col0 = strip * 1024;

  for (int st = 0; st < 16; ++st) {
    const int cb = col0 + st * 64;
    __syncthreads();
#pragma unroll
    for (int ii = 0; ii < 4; ++ii) {
      const int srow = w * 16 + ii * 4 + kq;
      const int chunk = n16 ^ (srow & 7);
      gload_lds16(Gh + (((size_t)(cb + srow)) << 7) + chunk * 8,
                  lh + ((w * 16 + ii * 4) << 7));
    }
    __syncthreads();   // drains vmcnt: staged tile visible to all waves
#pragma unroll
    for (int ct = 0; ct < 4; ++ct) {
      const int ar = ct * 16 + n16;
      const char* lbase = (const char*)lh + ar * 256;
      bf16x8 Ah[4];
#pragma unroll
      for (int q = 0; q < 4; ++q)
        Ah[q] = *(const bf16x8*)(lbase + ((q * 64 + kq * 16) ^ ((ar & 7) << 4)));
#pragma unroll
      for (int rg = 0; rg < 2; ++rg) {
        f32x4 p = {0.f, 0.f, 0.f, 0.f};
        f32x4 r = {0.f, 0.f, 0.f, 0.f};
#pragma unroll
        for (int q = 0; q < 4; ++q) {
          p = __builtin_amdgcn_mfma_f32_16x16x32_bf16(Ah[q], Bh[rg][q], p, 0, 0, 0);
          r = __builtin_amdgcn_mfma_f32_16x16x32_bf16(Ah[q], Bl[rg][q], r, 0, 0, 0);
        }
        const float tv = rg ? tau1 : tau0;
        const int lrow = w * 32 + rg * 16 + n16;     // block-local row 0..127
        const int row = rgrp * 128 + lrow;
#pragma unroll
        for (int i = 0; i < 4; ++i) {
          const float v = p[i] + r[i];
          if (v > tv) {
            const int c = cb + ct * 16 + kq * 4 + i;
            const int pos = atomicAdd(&cnt128[lrow], 1);   // LDS atomic
            if (pos < 32)
              gbuf[row * CAP_ + strip * 32 + pos] = make_int2(c, __float_as_int(v));
          }
        }
      }
    }
  }
  __syncthreads();
  if (tid < 128) gstripcnt[(rgrp * 128 + tid) * 16 + strip] = cnt128[tid];
}

// Top-32 by stored fp32 sim values via RANK-SCATTER on packed u64 keys.
// Also performs the count check; bad rows pushed to failq by lane 0.
__global__ __launch_bounds__(256) void k_refine(const int* __restrict__ gstripcnt,
                                                const int2* __restrict__ gbuf,
                                                int* __restrict__ topk_idx,
                                                int* __restrict__ failq,
                                                int* __restrict__ failn) {
  __shared__ u64 lk[4][CAP_];
  const int tid = threadIdx.x, w = tid >> 6, lane = tid & 63;
  const int n = blockIdx.x * 4 + w;

  const int scn = (lane < 16) ? gstripcnt[n * 16 + lane] : 0;
  int total = 0, over = 0;
#pragma unroll
  for (int s = 0; s < 16; ++s) {
    const int c = __shfl(scn, s, 64);
    total += c;
    over |= (c > 32);
  }
  const int bad = (total < 36 || total > CAP_ || over);
  const int cnt = bad ? 0 : total;

  // compact the 16 segments into lk[w][0..cnt)
  int base = 0;
#pragma unroll
  for (int s = 0; s < 16; ++s) {
    const int c = __shfl(scn, s, 64);
    if (!bad && lane < c) {
      const int2 p = gbuf[n * CAP_ + s * 32 + lane];
      u32 uv = (u32)p.y;
      uv = (uv >> 31) ? ~uv : (uv | 0x80000000u);
      lk[w][base + lane] = ((u64)uv << 32) | (u64)(16383 - p.x);
    }
    base += bad ? 0 : c;
  }
  __syncthreads();

  for (int ci = lane; ci < cnt; ci += 64) {
    const u64 kk = lk[w][ci];
    int r = 0;
#pragma unroll 4
    for (int j = 0; j < cnt; ++j)
      r += (lk[w][j] > kk) ? 1 : 0;
    if (r < 32) topk_idx[n * 32 + r] = 16383 - (int)(u32)(kk & 0xffffffffu);
  }
  if (bad) {
    if (lane == 0) {
      const int s = atomicAdd(failn, 1);
      if (s < 64) failq[s] = n;
    }
    if (lane < 32) topk_idx[n * 32 + lane] = 0;  // placeholder; fallback overwrites
  }
}

// exact fp64 full-row top-32 for statistically-failed rows (expected: none)
__global__ __launch_bounds__(256) void k_fallback(const float* __restrict__ x,
                                                  const int* __restrict__ failq,
                                                  const int* __restrict__ failn,
                                                  double* __restrict__ fsim,
                                                  int* __restrict__ topk_idx) {
  const int nf = *failn;
  const int which = blockIdx.x;
  if (which >= nf || which >= 64) return;
  const int row = failq[which];
  __shared__ float xs[128];
  __shared__ double bm[256];
  __shared__ int bc[256];
  const int tid = threadIdx.x;
  if (tid < 128) xs[tid] = x[row * 128 + tid];
  __syncthreads();
  double* fs = fsim + (size_t)which * 16384;
  for (int c = tid; c < 16384; c += 256) {
    const float4* xp = (const float4*)&x[c * 128];
    double a = 0.0;
    for (int d = 0; d < 32; ++d) {
      const float4 v = xp[d];
      a += (double)xs[d * 4 + 0] * (double)v.x + (double)xs[d * 4 + 1] * (double)v.y +
           (double)xs[d * 4 + 2] * (double)v.z + (double)xs[d * 4 + 3] * (double)v.w;
    }
    fs[c] = a;
  }
  __syncthreads();
  for (int r = 0; r < 32; ++r) {
    double m = -1.0e300; int mc = 0;
    for (int c = tid; c < 16384; c += 256) {
      const double v = fs[c];
      if (v > m || (v == m && c < mc)) { m = v; mc = c; }
    }
    bm[tid] = m; bc[tid] = mc;
    __syncthreads();
    for (int s = 128; s; s >>= 1) {
      if (tid < s) {
        if (bm[tid + s] > bm[tid] || (bm[tid + s] == bm[tid] && bc[tid + s] < bc[tid])) {
          bm[tid] = bm[tid + s]; bc[tid] = bc[tid + s];
        }
      }
      __syncthreads();
    }
    if (tid == 0) { topk_idx[row * 32 + r] = bc[0]; fs[bc[0]] = -1.0e300; }
    __syncthreads();
  }
}

// ------------------------------------------------------- attention ----------
// v3: 256 threads/node.  float2 gather (stride-130 LDS rows: 8B-aligned,
// <=2-way bank alias = free), score phase split 8-way over d, PV phase
// split 2-way over k.  Association changes are ~1e-7 value noise (no
// ranking semantics).  Ends at sa, written in place into qkbuf.
__global__ __launch_bounds__(256) void k_attn(const float* __restrict__ ego,
                                              float* __restrict__ qk,
                                              const int* __restrict__ topk_idx) {
  __shared__ float qv[128];
  __shared__ float sm[32 * 130];
  __shared__ int tki[32];
  __shared__ float sc[32];
  __shared__ float psum[256];
  const int n = blockIdx.x, tid = threadIdx.x;
  if (tid < 128) qv[tid] = qk[n * 128 + tid];
  if (tid < 32) tki[tid] = topk_idx[n * 32 + tid] & 16383;
  __syncthreads();
  // gather 32 rows x 64 float2 = 2048 float2; 256 threads x 8 iters
  for (int e = tid; e < 2048; e += 256) {
    const int k2 = e >> 6, d2 = e & 63;
    const float2 v = *(const float2*)&ego[(size_t)tki[k2] * 128 + d2 * 2];
    *(float2*)&sm[k2 * 130 + d2 * 2] = v;
  }
  __syncthreads();
  {
    const int kk = tid & 31, part = tid >> 5;    // 8 parts x 16 d each
    float s = 0.f;
    const int d0 = part * 16;
    for (int d = d0; d < d0 + 16; ++d) s += qv[d] * sm[kk * 130 + d];
    psum[tid] = s;
  }
  __syncthreads();
  if (tid < 32) {
    float v = 0.f;
#pragma unroll
    for (int p = 0; p < 8; ++p) v += psum[tid + p * 32];
    v *= (1.0f / 11.313708498984760f);    // 1/sqrt(128)
    float m = v;
#pragma unroll
    for (int off = 16; off; off >>= 1) m = fmaxf(m, __shfl_xor(m, off, 32));
    const float e = expf(v - m);
    float ssum = e;
#pragma unroll
    for (int off = 16; off; off >>= 1) ssum += __shfl_xor(ssum, off, 32);
    sc[tid] = e / ssum;
  }
  __syncthreads();
  {
    const int d = tid & 127, half = tid >> 7;    // 2 halves x 16 k each
    float s = 0.f;
    const int k0 = half * 16;
    for (int k2 = k0; k2 < k0 + 16; ++k2) s += sc[k2] * sm[k2 * 130 + d];
    psum[tid] = s;
  }
  __syncthreads();
  if (tid < 128) qk[n * 128 + tid] = psum[tid] + psum[tid + 128];
}

// ------------------------------------------- attnmm + fuse1 fused -----------
__global__ __launch_bounds__(256) void k_attnfuse(const float* __restrict__ sa,
                                                  const float* __restrict__ ego,
                                                  const float* __restrict__ allemb,
                                                  const float* __restrict__ wvT,
                                                  const float* __restrict__ bv,
                                                  const float* __restrict__ fwdT,
                                                  const float* __restrict__ fb,
                                                  float* __restrict__ atten,
                                                  float* __restrict__ z1,
                                                  float* __restrict__ z2,
                                                  float* __restrict__ cs1,
                                                  float* __restrict__ cs2) {
  __shared__ float xs[8][128];    // sa rows
  __shared__ float xa[8][128];    // allemb rows
  __shared__ float as_[8][128];   // atten rows (computed)
  __shared__ float red1[2][128];
  __shared__ float red2[2][128];
  const int tid = threadIdx.x;
  const int r0 = blockIdx.x * 8;
#pragma unroll
  for (int s = 0; s < 4; ++s) {
    const int idx = tid + s * 256;
    const int rr = idx >> 7, d = idx & 127;
    xs[rr][d] = sa[(r0 + rr) * 128 + d];
    xa[rr][d] = allemb[(r0 + rr) * 128 + d];
  }
  __syncthreads();
  const int j = tid & 127, h = tid >> 7;
  // phase 1: projection
  {
    const float bj = bv[j];
    float acc[4];
#pragma unroll
    for (int r = 0; r < 4; ++r) acc[r] = bj;
    for (int d = 0; d < 128; d += 4) {
      const float w0 = wvT[(d + 0) * 128 + j];
      const float w1 = wvT[(d + 1) * 128 + j];
      const float w2 = wvT[(d + 2) * 128 + j];
      const float w3 = wvT[(d + 3) * 128 + j];
#pragma unroll
      for (int r = 0; r < 4; ++r) {
        const float4 xv = *(const float4*)&xs[h * 4 + r][d];
        acc[r] += xv.x * w0 + xv.y * w1 + xv.z * w2 + xv.w * w3;
      }
    }
#pragma unroll
    for (int r = 0; r < 4; ++r) {
      const int n = r0 + h * 4 + r;
      const float av = acc[r] + 0.1f * ego[n * 128 + j];
      atten[n * 128 + j] = av;
      as_[h * 4 + r][j] = av;
    }
  }
  __syncthreads();
  // phase 2: fuse gating
  const float fbj = fb[j];
  float acc1[4], acc2[4];
#pragma unroll
  for (int r = 0; r < 4; ++r) { acc1[r] = fbj; acc2[r] = fbj; }
  for (int d = 0; d < 128; d += 4) {
    const float w0 = fwdT[(d + 0) * 128 + j];
    const float w1 = fwdT[(d + 1) * 128 + j];
    const float w2 = fwdT[(d + 2) * 128 + j];
    const float w3 = fwdT[(d + 3) * 128 + j];
#pragma unroll
    for (int r = 0; r < 4; ++r) {
      const int rr = h * 4 + r;
      const float4 xv = *(const float4*)&xa[rr][d];
      const float4 av = *(const float4*)&as_[rr][d];
      acc1[r] += xv.x * w0 + xv.y * w1 + xv.z * w2 + xv.w * w3;
      acc2[r] += av.x * w0 + av.y * w1 + av.z * w2 + av.w * w3;
    }
  }
  float ls1 = 0.f, ls2 = 0.f;
#pragma unroll
  for (int r = 0; r < 4; ++r) {
    const int rr = h * 4 + r;
    const float t1 = tanhf(acc1[r]);
    const float t2 = tanhf(acc2[r]);
    z1[(r0 + rr) * 128 + j] = t1;
    z2[(r0 + rr) * 128 + j] = t2;
    ls1 += expf(t1 - 1.0f);
    ls2 += expf(t2 - 1.0f);
  }
  red1[h][j] = ls1;
  red2[h][j] = ls2;
  __syncthreads();
  if (h == 0) {
    const int rep = blockIdx.x & 15;
    atomicAdd(&cs1[rep * 128 + j], red1[0][j] + red1[1][j]);
    atomicAdd(&cs2[rep * 128 + j], red2[0][j] + red2[1][j]);
  }
}

// v2: float4 body (was scalar over 2M elements); 2048 blocks x 256.
__global__ void k_fuse2(const float* __restrict__ allemb, const float* __restrict__ atten,
                        const float* __restrict__ z1, const float* __restrict__ z2,
                        const float* __restrict__ cs1, const float* __restrict__ cs2,
                        float* __restrict__ fusion) {
  __shared__ float s1[128], s2[128];
  const int tid = threadIdx.x;
  if (tid < 128) {
    float a = 0.f, b = 0.f;
#pragma unroll
    for (int rep = 0; rep < 16; ++rep) {
      a += cs1[rep * 128 + tid];
      b += cs2[rep * 128 + tid];
    }
    s1[tid] = a; s2[tid] = b;
  }
  __syncthreads();
  const int i = blockIdx.x * 256 + tid;          // float4 index, 524288 total
  const int j0 = (i & 31) * 4;
  const float4 zv1 = ((const float4*)z1)[i];
  const float4 zv2 = ((const float4*)z2)[i];
  const float4 xv = ((const float4*)allemb)[i];
  const float4 av = ((const float4*)atten)[i];
  float4 o;
  o.x = expf(zv1.x - 1.0f) / s1[j0 + 0] * xv.x + expf(zv2.x - 1.0f) / s2[j0 + 0] * av.x;
  o.y = expf(zv1.y - 1.0f) / s1[j0 + 1] * xv.y + expf(zv2.y - 1.0f) / s2[j0 + 1] * av.y;
  o.z = expf(zv1.z - 1.0f) / s1[j0 + 2] * xv.z + expf(zv2.z - 1.0f) / s2[j0 + 2] * av.z;
  o.w = expf(zv1.w - 1.0f) / s1[j0 + 3] * xv.w + expf(zv2.w - 1.0f) / s2[j0 + 3] * av.w;
  ((float4*)fusion)[i] = o;
}

// ---------------------------------------------------------------- launch ----
extern "C" void kernel_launch(void* const* d_in, const int* in_sizes, int n_in,
                              void* d_out, int out_size, void* d_ws, size_t ws_size,
                              hipStream_t stream) {
  (void)in_sizes; (void)n_in; (void)out_size; (void)ws_size;
  const float* user = (const float*)d_in[0];
  const float* item = (const float*)d_in[1];
  const int* adj_rows = (const int*)d_in[2];
  const int* adj_cols = (const int*)d_in[3];
  const float* adj_vals = (const float*)d_in[4];
  const float* wq = (const float*)d_in[5];
  const float* bq = (const float*)d_in[6];
  const float* wk = (const float*)d_in[7];
  const float* wv = (const float*)d_in[9];
  const float* bv = (const float*)d_in[10];
  const float* fw = (const float*)d_in[11];
  const float* fb = (const float*)d_in[12];

  float* out = (float*)d_out;
  float* allemb = out;                    // [N,D]
  float* atten = out + (size_t)N_ * D_;   // [N,D]
  float* fusion = out + (size_t)2 * N_ * D_;

  char* ws = (char*)d_ws;
  size_t off = 0;
  auto alloc = [&](size_t bytes) { char* p = ws + off; off += (bytes + 255) & ~(size_t)255; return p; };
  float* ego_a = (float*)alloc((size_t)N_ * D_ * 4);
  float* ego_b = (float*)alloc((size_t)N_ * D_ * 4);
  float* qkbuf = (float*)alloc((size_t)N_ * D_ * 4);
  u16* Gh = (u16*)alloc((size_t)N_ * D_ * 2);
  u16* Gl = (u16*)alloc((size_t)N_ * D_ * 2);
  u16* XTh = (u16*)alloc((size_t)N_ * D_ * 2);
  u16* XTl = (u16*)alloc((size_t)N_ * D_ * 2);
  int2* gbuf = (int2*)alloc((size_t)N_ * CAP_ * 8);  // (col,val) pairs (aliased by z1)
  float* z1 = (float*)gbuf;                          // lifetimes disjoint
  float* z2 = (float*)alloc((size_t)N_ * D_ * 4);
  int* topk_idx = (int*)alloc((size_t)N_ * 32 * 4);
  int* ccol = (int*)alloc((size_t)E_ * 4);
  float* cval = (float*)alloc((size_t)E_ * 4);
  int* cnt = (int*)alloc((size_t)N_ * 4);
  int* row_ptr = (int*)alloc((size_t)(N_ + 1) * 4);
  int* cursor = (int*)alloc((size_t)N_ * 4);
  float* M = (float*)alloc(128 * 128 * 4);
  float* bqk = (float*)alloc(128 * 4);
  float* wvT = (float*)alloc(128 * 128 * 4);
  float* fwdT = (float*)alloc(128 * 128 * 4);
  float* cs1 = (float*)alloc(16 * 128 * 4);           // 16 replicas
  float* cs2 = (float*)alloc(16 * 128 * 4);
  float* C2 = (float*)alloc(128 * 128 * 4);
  float* C2part = (float*)alloc((size_t)256 * 16384 * 4);   // 16 MB partials
  float* svec = (float*)alloc(128 * 4);
  float* tau = (float*)alloc((size_t)N_ * 4);
  int* gcount = (int*)alloc((size_t)N_ * 4);          // legacy (unused by hot path)
  int* gstripcnt = (int*)alloc((size_t)N_ * 16 * 4);  // per (row,strip) counts
  int* failq = (int*)alloc(64 * 4);
  int* failn = (int*)alloc(4);
  double* fsim = (double*)alloc((size_t)64 * N_ * 8);

  k_init<<<64, 256, 0, stream>>>(wq, wk, bq, wv, fw, M, bqk, wvT, fwdT, cnt, cs1, cs2, svec, gcount, failn);
  k_concat<<<2048, 256, 0, stream>>>(user, item, ego_a, adj_rows, cnt);   // float4 + hist
  k_scan<<<1, 1024, 0, stream>>>(cnt, row_ptr, cursor);
  k_scatter<<<2048, 256, 0, stream>>>(adj_rows, adj_cols, adj_vals, cursor, ccol, cval);

  k_spmm<<<N_, 128, 0, stream>>>(ego_a, ego_b, allemb, row_ptr, ccol, cval, 1, 0);
  k_spmm<<<N_, 128, 0, stream>>>(ego_b, ego_a, allemb, row_ptr, ccol, cval, 0, 0);
  k_spmm<<<N_, 128, 0, stream>>>(ego_a, ego_b, allemb, row_ptr, ccol, cval, 0, 1);
  // ego3 = ego_b; allemb = mean of layers (div folded into last pass)

  k_split_t<<<256, 256, 0, stream>>>(ego_b, Gh, Gl, XTh, XTl, svec);
  k_c2mfma<<<256, 256, 0, stream>>>(XTh, XTl, C2part);
  k_c2red<<<64, 256, 0, stream>>>(C2part, C2);
  k_tau<<<2048, 128, 0, stream>>>(ego_b, C2, svec, tau);

  k_qk<<<2048, 256, 0, stream>>>(ego_b, M, bqk, qkbuf);
  k_simmfma<<<2048, 256, 0, stream>>>(Gh, Gl, tau, gstripcnt, gbuf);
  k_refine<<<4096, 256, 0, stream>>>(gstripcnt, gbuf, topk_idx, failq, failn);
  k_fallback<<<64, 256, 0, stream>>>(ego_b, failq, failn, fsim, topk_idx);
  k_attn<<<N_, 256, 0, stream>>>(ego_b, qkbuf, topk_idx);          // v3 -> sa in qkbuf
  k_attnfuse<<<2048, 256, 0, stream>>>(qkbuf, ego_b, allemb, wvT, bv, fwdT, fb,
                                       atten, z1, z2, cs1, cs2);
  k_fuse2<<<2048, 256, 0, stream>>>(allemb, atten, z1, z2, cs1, cs2, fusion);
}